// Round 5
// baseline (340.859 us; speedup 1.0000x reference)
//
#include <hip/hip_runtime.h>
#include <hip/hip_bf16.h>

// ---------------- problem constants ----------------
constexpr int U_  = 51200;
constexpr int I_  = 25600;
constexpr int E_  = 1000000;
constexpr int EP_ = 100000;
constexpr int CB_ = 256;                 // contrastive chunk size
constexpr int NCHUNK_ = U_ / CB_;        // 200
constexpr size_t UD_ = (size_t)U_ * 64;
constexpr size_t ID_ = (size_t)I_ * 64;
constexpr int NBK_ = 200;                // buckets per side
constexpr int CAP_ = 8192;               // record slots per bucket
constexpr int TILE_ = 1024;              // edges per Phase-A block (small => 14.7KB LDS => 8 blk/CU)
constexpr int NBA_ = (E_ + TILE_ - 1) / TILE_;  // 977
constexpr int NANC_ = U_ / 16;           // 3200 anchor blocks
constexpr int NCVT_ = (int)((UD_ + ID_) / (8 * 256));  // 2400 convert blocks (8 elem/thread)
constexpr int NSCB_ = (2 * EP_) / 16;    // 12500 score blocks (16 edges/block)

// fp8 scaling (values sit in e4m3 sweet range)
constexpr float SCALE_E_  = 16.f;   // raw embeddings ~0.1
constexpr float ISCALE_E_ = 1.f / 16.f;
constexpr float SCALE_1_  = 64.f;   // layer-1 aggregates ~0.02
constexpr float ISCALE_1_ = 1.f / 64.f;

// ---------------- workspace layout (4-byte element offsets) ----------------
constexpr size_t OFF_LOSS  = 0;
constexpr size_t OFF_FLAG  = 1;
constexpr size_t OFF_CURU  = 8;                      // 200 ints
constexpr size_t OFF_CURI  = 208;                    // 200 ints
constexpr size_t OFF_VEC   = 448;                    // 192 floats
constexpr size_t OFF_ROWU  = 1088;                   // U_+1
constexpr size_t OFF_ROWI  = ((OFF_ROWU + U_ + 1 + 63) / 64) * 64;   // I_+1
constexpr size_t OFF_CSRU  = ((OFF_ROWI + I_ + 1 + 63) / 64) * 64;   // E_
constexpr size_t OFF_CSRI  = OFF_CSRU + E_;          // E_
constexpr size_t OFF_U1    = ((OFF_CSRI + E_ + 63) / 64) * 64;       // UD_ (bf16)
constexpr size_t OFF_I1    = OFF_U1 + UD_;
constexpr size_t OFF_HU    = OFF_I1 + ID_;           // bufU aliases
constexpr size_t OFF_HI    = OFF_HU + UD_;           // bufI aliases
constexpr size_t OFF_ANC   = OFF_HI + ID_;
constexpr size_t OFF_UE8   = OFF_ANC + UD_;          // UD_ bytes (fp8)
constexpr size_t OFF_IE8   = OFF_UE8 + UD_ / 4;
constexpr size_t OFF_U18   = OFF_IE8 + ID_ / 4;
constexpr size_t OFF_I18   = OFF_U18 + UD_ / 4;
// total ≈ 65.6 MB

#define DEVI static __device__ __forceinline__

typedef _Float16 h2v __attribute__((ext_vector_type(2)));
typedef _Float16 f16x8 __attribute__((ext_vector_type(8)));
typedef float floatx4 __attribute__((ext_vector_type(4)));
typedef unsigned short u16x8 __attribute__((ext_vector_type(8)));

DEVI float b2f(__hip_bfloat16 x) { return __bfloat162float(x); }

DEVI float bfb2f(unsigned short b) {
  unsigned u = ((unsigned)b) << 16; float f; __builtin_memcpy(&f, &u, 4); return f;
}

DEVI float ldf(const void* p, size_t i, int isf32) {
  if (isf32) return ((const float*)p)[i];
  return b2f(((const __hip_bfloat16*)p)[i]);
}

DEVI float frcp(float x) { return __builtin_amdgcn_rcpf(x); }

DEVI float fexp2(float x) {
#if __has_builtin(__builtin_amdgcn_exp2f)
  return __builtin_amdgcn_exp2f(x);
#else
  return exp2f(x);
#endif
}

// fp8 e4m3 (OCP) decode/encode
DEVI float fp8_dec(unsigned v) {
#if __has_builtin(__builtin_amdgcn_cvt_f32_fp8)
  return __builtin_amdgcn_cvt_f32_fp8(v, 0);
#else
  unsigned b = v & 0xFF;
  if (!(b & 0x78)) return 0.f;  // flush subnormals (negligible at our scales)
  unsigned short h = (unsigned short)(((b & 0x80) << 8) | (((b & 0x7f) + (8 << 3)) << 7));
  _Float16 hf; __builtin_memcpy(&hf, &h, 2);
  return (float)hf;
#endif
}

// decode byte `s` (compile-time literal) of dword w
#if __has_builtin(__builtin_amdgcn_cvt_f32_fp8)
#define FP8D(w, s) __builtin_amdgcn_cvt_f32_fp8((w), (s))
#else
#define FP8D(w, s) fp8_dec(((w) >> (8 * (s))) & 0xFF)
#endif

DEVI unsigned fp8_enc_pk(float a, float b) {
#if __has_builtin(__builtin_amdgcn_cvt_pk_fp8_f32)
  return __builtin_amdgcn_cvt_pk_fp8_f32(a, b, 0u, false);
#else
  auto enc1 = [](float f) -> unsigned {
    _Float16 hf = (_Float16)f; unsigned short hb; __builtin_memcpy(&hb, &hf, 2);
    int s = hb >> 15, e = (hb >> 10) & 31, m = hb & 1023;
    int e8 = e - 15 + 7;
    int m3 = (m + ((1 << 6) + ((m >> 7) & 1))) >> 7;
    if (m3 > 7) { m3 = 0; e8++; }
    if (e8 <= 0) return (unsigned)(s << 7);
    if (e8 > 15) { e8 = 15; m3 = 6; }
    return (unsigned)((s << 7) | (e8 << 3) | m3);
  };
  return enc1(a) | (enc1(b) << 8);
#endif
}

DEVI int waveInclScan(int v, int lane) {
  #pragma unroll
  for (int off = 1; off < 64; off <<= 1) {
    int t = __shfl_up(v, off, 64);
    if (lane >= off) v += t;
  }
  return v;
}

// ---------------- 0. prep (also zeroes loss + bucket counters) ----------------
__global__ void prep_kernel(const unsigned short* __restrict__ ueu,
                            const void* __restrict__ W, const void* __restrict__ a,
                            const void* __restrict__ WU, const void* __restrict__ aU,
                            float* __restrict__ vecs, float* __restrict__ flag,
                            float* __restrict__ ws0) {
  int tid = threadIdx.x;
  for (int i = tid; i < 408; i += 256)
    if (i == 0 || i >= 8) ws0[i] = 0.f;
  if (tid < 64) {
    int cnt = 0;
    for (int i = 0; i < 256; i++) {
      int e = (ueu[i] >> 7) & 0xFF;
      if (e >= 130) cnt++;
    }
    int isf32 = (cnt >= 8);
    if (tid == 0) *flag = isf32 ? 1.0f : 0.0f;
    int d = tid;
    float s = 0.f, t1 = 0.f, t2 = 0.f;
    for (int e = 0; e < 64; e++) {
      s += ldf(W, d * 64 + e, isf32) * ldf(a, e, isf32);
      float wue = ldf(WU, d * 64 + e, isf32);
      t1 += wue * ldf(aU, e, isf32);
      t2 += wue * ldf(aU, 64 + e, isf32);
    }
    vecs[d] = s;
    vecs[64 + d] = t1;
    vecs[128 + d] = t2;
  }
}

// ---------------- fused A: bucketA + anchor + fp8-convert -------------
struct BktSmem {            // ~14.7 KB at TILE_=1024
  int histU[NBK_], histI[NBK_];
  int loffU[NBK_ + 1], loffI[NBK_ + 1];
  int cbU[NBK_], cbI[NBK_];
  int lcU[NBK_], lcI[NBK_];
  int wsU[4], wsI[4];
  unsigned recsU[TILE_], recsI[TILE_];
};
constexpr int WS_ = 72;
struct AncSmem {            // ~11.6 KB
  _Float16 WUt[64 * WS_];
  _Float16 mixS[16 * WS_];
  float invSe[16];
  int nbrS[128];
};
constexpr size_t FSA_SMEM = sizeof(BktSmem) > sizeof(AncSmem) ? sizeof(BktSmem) : sizeof(AncSmem);

DEVI void bucketA_body(char* smemRaw, int blk,
    const int* __restrict__ rs, const int* __restrict__ rd,
    unsigned* __restrict__ bufU, unsigned* __restrict__ bufI,
    int* __restrict__ curU, int* __restrict__ curI) {
  BktSmem& S = *(BktSmem*)smemRaw;
  int tid = threadIdx.x;
  int base = blk * TILE_;
  for (int i = tid; i < NBK_; i += 256) { S.histU[i] = 0; S.histI[i] = 0; }
  __syncthreads();
  int ss[4], dd[4];
  #pragma unroll
  for (int t = 0; t < 4; t++) {
    int e = base + t * 256 + tid;
    bool v = e < E_;
    ss[t] = v ? rs[e] : -1;
    dd[t] = v ? rd[e] : 0;
    if (v) {
      atomicAdd(&S.histU[ss[t] >> 8], 1);
      atomicAdd(&S.histI[dd[t] >> 7], 1);
    }
  }
  __syncthreads();
  if (tid < NBK_) {
    int cU = S.histU[tid];
    S.cbU[tid] = tid * CAP_ + (cU ? atomicAdd(&curU[tid], cU) : 0);
    int cI = S.histI[tid];
    S.cbI[tid] = tid * CAP_ + (cI ? atomicAdd(&curI[tid], cI) : 0);
  }
  int lane = tid & 63, wv = tid >> 6;
  int cvU = (tid < NBK_) ? S.histU[tid] : 0;
  int cvI = (tid < NBK_) ? S.histI[tid] : 0;
  int inU = waveInclScan(cvU, lane);
  int inI = waveInclScan(cvI, lane);
  if (lane == 63) { S.wsU[wv] = inU; S.wsI[wv] = inI; }
  __syncthreads();
  int woU = 0, woI = 0;
  for (int w = 0; w < wv; w++) { woU += S.wsU[w]; woI += S.wsI[w]; }
  if (tid < NBK_) {
    S.loffU[tid] = woU + inU - cvU;
    S.loffI[tid] = woI + inI - cvI;
  }
  if (tid == NBK_ - 1) {
    S.loffU[NBK_] = woU + inU;
    S.loffI[NBK_] = woI + inI;
  }
  __syncthreads();
  if (tid < NBK_) { S.lcU[tid] = S.loffU[tid]; S.lcI[tid] = S.loffI[tid]; }
  __syncthreads();
  #pragma unroll
  for (int t = 0; t < 4; t++) {
    if (ss[t] >= 0) {
      int b = ss[t] >> 8;
      int p = atomicAdd(&S.lcU[b], 1);
      S.recsU[p] = ((unsigned)(ss[t] & 255) << 17) | (unsigned)dd[t];
      b = dd[t] >> 7;
      p = atomicAdd(&S.lcI[b], 1);
      S.recsI[p] = ((unsigned)(dd[t] & 127) << 17) | (unsigned)ss[t];
    }
  }
  __syncthreads();
  int totU = S.loffU[NBK_];
  for (int p = tid; p < totU; p += 256) {
    int lo = 0, hi = NBK_;
    while (hi - lo > 1) { int mid = (lo + hi) >> 1; if (S.loffU[mid] <= p) lo = mid; else hi = mid; }
    bufU[S.cbU[lo] + (p - S.loffU[lo])] = S.recsU[p];
  }
  int totI = S.loffI[NBK_];
  for (int p = tid; p < totI; p += 256) {
    int lo = 0, hi = NBK_;
    while (hi - lo > 1) { int mid = (lo + hi) >> 1; if (S.loffI[mid] <= p) lo = mid; else hi = mid; }
    bufI[S.cbI[lo] + (p - S.loffI[lo])] = S.recsI[p];
  }
}

// anchor: FFT-filter + neighbor attention (distributed multi-value reductions)
DEVI void anchor_body(char* smemRaw, int blk,
    const void* __restrict__ ue, const void* __restrict__ WU,
    const void* __restrict__ cw, const float* __restrict__ vecs,
    const int* __restrict__ nbr, float* __restrict__ out, int isf32) {
  AncSmem& S = *(AncSmem*)smemRaw;
  int tid = threadIdx.x;
  int wv = tid >> 6, lane = tid & 63;
  int ublk = blk * 16;

  #pragma unroll
  for (int it = 0; it < 16; it++) {
    int k = it * 4 + wv;
    S.WUt[lane * WS_ + k] = (_Float16)ldf(WU, (size_t)k * 64 + lane, isf32);
  }
  if (tid < 128) S.nbrS[tid] = nbr[ublk * 8 + tid];
  __syncthreads();

  float cw0 = ldf(cw, (0 * 64 + lane) * 2, isf32);
  float w1r = ldf(cw, (1 * 64 + lane) * 2, isf32), w1i = ldf(cw, (1 * 64 + lane) * 2 + 1, isf32);
  float w2r = ldf(cw, (2 * 64 + lane) * 2, isf32), w2i = ldf(cw, (2 * 64 + lane) * 2 + 1, isf32);
  float w3r = ldf(cw, (3 * 64 + lane) * 2, isf32), w3i = ldf(cw, (3 * 64 + lane) * 2 + 1, isf32);
  float cw4 = ldf(cw, (4 * 64 + lane) * 2, isf32);
  float v1 = vecs[64 + lane], v2 = vecs[128 + lane];
  const float c1 = 0.70710678118654752440f;

  bool b3 = (lane & 8) != 0, b4 = (lane & 16) != 0, b5 = (lane & 32) != 0;

  // q for the wave's 4 users: distributed reduce over lane-bit-{4,5}
  float qv0 = ldf(ue, (size_t)(ublk + wv * 4 + 0) * 64 + lane, isf32) * v2;
  float qv1 = ldf(ue, (size_t)(ublk + wv * 4 + 1) * 64 + lane, isf32) * v2;
  float qv2 = ldf(ue, (size_t)(ublk + wv * 4 + 2) * 64 + lane, isf32) * v2;
  float qv3 = ldf(ue, (size_t)(ublk + wv * 4 + 3) * 64 + lane, isf32) * v2;
  qv0 += __shfl_xor(qv0, 16, 64); qv0 += __shfl_xor(qv0, 32, 64);
  qv1 += __shfl_xor(qv1, 16, 64); qv1 += __shfl_xor(qv1, 32, 64);
  qv2 += __shfl_xor(qv2, 16, 64); qv2 += __shfl_xor(qv2, 32, 64);
  qv3 += __shfl_xor(qv3, 16, 64); qv3 += __shfl_xor(qv3, 32, 64);
  float qs0 = b4 ? qv1 : qv0;
  float qs1 = b4 ? qv3 : qv2;
  float qw = b5 ? qs1 : qs0;
  qw += __shfl_xor(qw, 1, 64); qw += __shfl_xor(qw, 2, 64);
  qw += __shfl_xor(qw, 4, 64); qw += __shfl_xor(qw, 8, 64);
  // lane l now holds Q[l>>4]

  float xc[8], xn[8];
  #pragma unroll
  for (int k = 0; k < 8; k++)
    xc[k] = ldf(ue, (size_t)S.nbrS[wv * 32 + k] * 64 + lane, isf32);

  for (int u4 = 0; u4 < 4; u4++) {
    int uL = wv * 4 + u4;
    if (u4 < 3) {
      #pragma unroll
      for (int k = 0; k < 8; k++)
        xn[k] = ldf(ue, (size_t)S.nbrS[wv * 32 + (u4 + 1) * 8 + k] * 64 + lane, isf32);
    }
    float sA = xc[1] - xc[3] - xc[5] + xc[7];
    float sB = xc[1] + xc[3] - xc[5] - xc[7];
    float ev = (xc[0] + xc[4]) + (xc[2] + xc[6]);
    float od = (xc[1] + xc[5]) + (xc[3] + xc[7]);
    float d04 = xc[0] - xc[4], d26 = xc[2] - xc[6];
    float X0r = ev + od;
    float X1r = d04 + c1 * sA;
    float X1i = -d26 - c1 * sB;
    float X2r = (xc[0] + xc[4]) - (xc[2] + xc[6]);
    float X2i = -(xc[1] - xc[3] + xc[5] - xc[7]);
    float X3r = d04 - c1 * sA;
    float X3i = d26 - c1 * sB;
    float X4r = ev - od;
    float Zr0 = X0r * cw0;
    float Zr1 = X1r * w1r - X1i * w1i, Zi1 = X1r * w1i + X1i * w1r;
    float Zr2 = X2r * w2r - X2i * w2i, Zi2 = X2r * w2i + X2i * w2r;
    float Zr3 = X3r * w3r - X3i * w3i, Zi3 = X3r * w3i + X3i * w3r;
    float Zr4 = X4r * cw4;
    float eP = Zr0 + Zr4, eM = Zr0 - Zr4;
    float t1 = c1 * (Zr1 - Zr3), t2 = c1 * (Zi1 + Zi3);
    float y[8];
    y[0] = eP + 2.f * (Zr1 + Zr2 + Zr3);
    y[1] = eM + 2.f * (t1 - t2 - Zi2);
    y[2] = eP + 2.f * (-Zi1 - Zr2 + Zi3);
    y[3] = eM + 2.f * (-t1 - t2 + Zi2);
    y[4] = eP + 2.f * (-Zr1 + Zr2 - Zr3);
    y[5] = eM + 2.f * (-t1 + t2 - Zi2);
    y[6] = eP + 2.f * (Zi1 - Zr2 - Zi3);
    y[7] = eM + 2.f * (t1 + t2 + Zi2);
    #pragma unroll
    for (int k = 0; k < 8; k++) y[k] *= 0.125f;

    // 8 dot-products vs v1: distributed reduce
    float p0 = y[0] * v1, p1 = y[1] * v1, p2 = y[2] * v1, p3 = y[3] * v1;
    float p4 = y[4] * v1, p5 = y[5] * v1, p6 = y[6] * v1, p7 = y[7] * v1;
    p0 += __shfl_xor(p0, 8, 64);  p0 += __shfl_xor(p0, 16, 64); p0 += __shfl_xor(p0, 32, 64);
    p1 += __shfl_xor(p1, 8, 64);  p1 += __shfl_xor(p1, 16, 64); p1 += __shfl_xor(p1, 32, 64);
    p2 += __shfl_xor(p2, 8, 64);  p2 += __shfl_xor(p2, 16, 64); p2 += __shfl_xor(p2, 32, 64);
    p3 += __shfl_xor(p3, 8, 64);  p3 += __shfl_xor(p3, 16, 64); p3 += __shfl_xor(p3, 32, 64);
    p4 += __shfl_xor(p4, 8, 64);  p4 += __shfl_xor(p4, 16, 64); p4 += __shfl_xor(p4, 32, 64);
    p5 += __shfl_xor(p5, 8, 64);  p5 += __shfl_xor(p5, 16, 64); p5 += __shfl_xor(p5, 32, 64);
    p6 += __shfl_xor(p6, 8, 64);  p6 += __shfl_xor(p6, 16, 64); p6 += __shfl_xor(p6, 32, 64);
    p7 += __shfl_xor(p7, 8, 64);  p7 += __shfl_xor(p7, 16, 64); p7 += __shfl_xor(p7, 32, 64);
    float a0 = b3 ? p1 : p0;
    float a1 = b3 ? p3 : p2;
    float a2 = b3 ? p5 : p4;
    float a3 = b3 ? p7 : p6;
    float c0 = b4 ? a1 : a0;
    float c1s = b4 ? a3 : a2;
    float w = b5 ? c1s : c0;
    w += __shfl_xor(w, 1, 64); w += __shfl_xor(w, 2, 64); w += __shfl_xor(w, 4, 64);
    // lane l holds EK[l>>3]

    float qu = __shfl(qw, u4 * 16, 64);
    float v = w + qu;
    v = v > 0.f ? v : 0.1f * v;              // LeakyReLU(0.1)
    float m = v;
    m = fmaxf(m, __shfl_xor(m, 8, 64));
    m = fmaxf(m, __shfl_xor(m, 16, 64));
    m = fmaxf(m, __shfl_xor(m, 32, 64));
    float wexp = __expf(v - m);
    float se = wexp;
    se += __shfl_xor(se, 8, 64); se += __shfl_xor(se, 16, 64); se += __shfl_xor(se, 32, 64);
    float mix = 0.f;
    #pragma unroll
    for (int k = 0; k < 8; k++)
      mix += __shfl(wexp, k * 8, 64) * y[k];
    S.mixS[uL * WS_ + lane] = (_Float16)mix;
    if (lane == 0) S.invSe[uL] = frcp(se);
    #pragma unroll
    for (int k = 0; k < 8; k++) xc[k] = xn[k];
  }
  __syncthreads();

  int n = lane & 15, qd = lane >> 4;
  f16x8 A0 = *(const f16x8*)&S.mixS[(lane & 15) * WS_ + qd * 8];
  f16x8 A1 = *(const f16x8*)&S.mixS[(lane & 15) * WS_ + 32 + qd * 8];
  f16x8 B0 = *(const f16x8*)&S.WUt[(wv * 16 + n) * WS_ + qd * 8];
  f16x8 B1 = *(const f16x8*)&S.WUt[(wv * 16 + n) * WS_ + 32 + qd * 8];
  const floatx4 zero = {0.f, 0.f, 0.f, 0.f};
  floatx4 acc = __builtin_amdgcn_mfma_f32_16x16x32_f16(A0, B0, zero, 0, 0, 0);
  acc = __builtin_amdgcn_mfma_f32_16x16x32_f16(A1, B1, acc, 0, 0, 0);
  #pragma unroll
  for (int r = 0; r < 4; r++) {
    int m = qd * 4 + r;
    out[(size_t)(ublk + m) * 64 + wv * 16 + n] = acc[r] * S.invSe[m];
  }
}

// 8 elements per thread, vector loads (fp32: 2×float4, bf16: 1×ushort8)
DEVI void convert_body(int blk, const void* __restrict__ ue, const void* __restrict__ ie,
                       unsigned char* __restrict__ ue8, unsigned char* __restrict__ ie8,
                       int isf32) {
  size_t t = (size_t)blk * 256 + threadIdx.x;   // 8-element group index
  const void* src; unsigned* dst; size_t o;
  if (t < UD_ / 8) { src = ue; dst = (unsigned*)ue8; o = t; }
  else             { src = ie; dst = (unsigned*)ie8; o = t - UD_ / 8; }
  float v[8];
  if (isf32) {
    float4 f0 = ((const float4*)src)[2 * o];
    float4 f1 = ((const float4*)src)[2 * o + 1];
    v[0] = f0.x; v[1] = f0.y; v[2] = f0.z; v[3] = f0.w;
    v[4] = f1.x; v[5] = f1.y; v[6] = f1.z; v[7] = f1.w;
  } else {
    u16x8 h = ((const u16x8*)src)[o];
    #pragma unroll
    for (int i = 0; i < 8; i++) v[i] = bfb2f(h[i]);
  }
  unsigned lo = fp8_enc_pk(v[0] * SCALE_E_, v[1] * SCALE_E_) |
                (fp8_enc_pk(v[2] * SCALE_E_, v[3] * SCALE_E_) << 16);
  unsigned hi = fp8_enc_pk(v[4] * SCALE_E_, v[5] * SCALE_E_) |
                (fp8_enc_pk(v[6] * SCALE_E_, v[7] * SCALE_E_) << 16);
  dst[2 * o]     = lo;
  dst[2 * o + 1] = hi;
}

__global__ __launch_bounds__(256) void fusedA_kernel(
    const int* __restrict__ rs, const int* __restrict__ rd,
    unsigned* __restrict__ bufU, unsigned* __restrict__ bufI,
    int* __restrict__ curU, int* __restrict__ curI,
    const void* __restrict__ ue, const void* __restrict__ ie,
    const void* __restrict__ WU, const void* __restrict__ cw,
    const float* __restrict__ vecs, const int* __restrict__ nbr,
    float* __restrict__ anc, unsigned char* __restrict__ ue8,
    unsigned char* __restrict__ ie8, const float* __restrict__ flag) {
  __shared__ __align__(16) char smem[FSA_SMEM];
  if (blockIdx.x < NBA_) {
    bucketA_body(smem, blockIdx.x, rs, rd, bufU, bufI, curU, curI);
  } else if (blockIdx.x < NBA_ + NANC_) {
    anchor_body(smem, blockIdx.x - NBA_, ue, WU, cw, vecs, nbr, anc, *flag > 0.5f);
  } else {
    convert_body(blockIdx.x - NBA_ - NANC_, ue, ie, ue8, ie8, *flag > 0.5f);
  }
}

// ---------------- 1c. Phase B (with per-block local bucket scan) ----------------
struct BktBSmem {
  int stage[CAP_];
  int cntk[256], offk[256];
  int exclS[256];
  int wsum[4], wsum2[4];
};

__global__ __launch_bounds__(256) void bucketB_kernel(
    const unsigned* __restrict__ bufU, const unsigned* __restrict__ bufI,
    const int* __restrict__ curU, const int* __restrict__ curI,
    int* __restrict__ rowU, int* __restrict__ rowI,
    int* __restrict__ csrU, int* __restrict__ csrI) {
  __shared__ __align__(16) BktBSmem S;
  int tid = threadIdx.x, b = blockIdx.x;
  int side = b >= NBK_;
  int bb = side ? b - NBK_ : b;
  const unsigned* src = (side ? bufI : bufU) + (size_t)bb * CAP_;
  const int* cur = side ? curI : curU;
  int total = cur[bb];
  int kpb   = side ? 128 : 256;
  int* rowptr = side ? rowI : rowU;
  int* csr    = side ? csrI : csrU;
  if (b == 0 && tid == 0) { rowU[U_] = E_; rowI[I_] = E_; }
  int lane = tid & 63, wv = tid >> 6;
  // local exclusive scan of cur[0..NBK_) -> gbase
  {
    int v = (tid < NBK_) ? cur[tid] : 0;
    int incl = waveInclScan(v, lane);
    if (lane == 63) S.wsum2[wv] = incl;
    S.cntk[tid] = 0;
    __syncthreads();
    int off = 0;
    for (int w = 0; w < wv; w++) off += S.wsum2[w];
    if (tid < NBK_) S.exclS[tid] = off + incl - v;
    __syncthreads();
  }
  int gbase = S.exclS[bb];
  for (int r = tid; r < total; r += 256) atomicAdd(&S.cntk[src[r] >> 17], 1);
  __syncthreads();
  int cv = (tid < kpb) ? S.cntk[tid] : 0;
  int incl = waveInclScan(cv, lane);
  if (lane == 63) S.wsum[wv] = incl;
  __syncthreads();
  int wvoff = 0;
  for (int w = 0; w < wv; w++) wvoff += S.wsum[w];
  int excl = wvoff + incl - cv;
  if (tid < kpb) {
    S.offk[tid] = excl;
    rowptr[bb * kpb + tid] = gbase + excl;
  }
  __syncthreads();
  for (int r = tid; r < total; r += 256) {
    unsigned rec = src[r];
    int slot = atomicAdd(&S.offk[rec >> 17], 1);
    if (slot < CAP_) S.stage[slot] = (int)(rec & 0x1FFFFu);
  }
  __syncthreads();
  for (int s = tid; s < total; s += 256) csr[gbase + s] = S.stage[s];
}

// ---------------- 2. fused layer-1 aggregation (fp8 dword gather, bf16+fp8 out) -------
// lane = sub*16 + c16; each lane loads one dword (4 fp8 cols) of edge csr[j+sub]
__global__ __launch_bounds__(256) void agg1_kernel(
    const unsigned char* __restrict__ ue8, const unsigned char* __restrict__ ie8,
    const int* __restrict__ rowU, const int* __restrict__ rowI,
    const int* __restrict__ csrU, const int* __restrict__ csrI,
    __hip_bfloat16* __restrict__ u1, __hip_bfloat16* __restrict__ i1,
    unsigned char* __restrict__ u18, unsigned char* __restrict__ i18) {
  int wv = threadIdx.x >> 6, lane = threadIdx.x & 63;
  int sub = lane >> 4, c16 = lane & 15;
  int side = blockIdx.x >= I_ / 4;          // 0: item rows (gather ue8), 1: user rows
  int blk = side ? blockIdx.x - I_ / 4 : blockIdx.x;
  int r = blk * 4 + wv;
  const int* row = side ? rowU : rowI;
  const int* csr = side ? csrU : csrI;
  const unsigned char* src = side ? ie8 : ue8;
  __hip_bfloat16* out = side ? u1 : i1;
  unsigned char* out8 = side ? u18 : i18;
  int s0 = row[r], s1 = row[r + 1];
  float a4[4] = {0.f, 0.f, 0.f, 0.f};
  int j = s0;
  for (; j + 16 <= s1; j += 16) {        // 4 gathers in flight
    int e0 = csr[j + sub], e1 = csr[j + 4 + sub];
    int e2 = csr[j + 8 + sub], e3 = csr[j + 12 + sub];
    unsigned w0 = *(const unsigned*)(src + (size_t)e0 * 64 + c16 * 4);
    unsigned w1 = *(const unsigned*)(src + (size_t)e1 * 64 + c16 * 4);
    unsigned w2 = *(const unsigned*)(src + (size_t)e2 * 64 + c16 * 4);
    unsigned w3 = *(const unsigned*)(src + (size_t)e3 * 64 + c16 * 4);
    a4[0] += (FP8D(w0, 0) + FP8D(w1, 0)) + (FP8D(w2, 0) + FP8D(w3, 0));
    a4[1] += (FP8D(w0, 1) + FP8D(w1, 1)) + (FP8D(w2, 1) + FP8D(w3, 1));
    a4[2] += (FP8D(w0, 2) + FP8D(w1, 2)) + (FP8D(w2, 2) + FP8D(w3, 2));
    a4[3] += (FP8D(w0, 3) + FP8D(w1, 3)) + (FP8D(w2, 3) + FP8D(w3, 3));
  }
  if (j + 8 <= s1) {
    int e0 = csr[j + sub], e1 = csr[j + 4 + sub];
    unsigned w0 = *(const unsigned*)(src + (size_t)e0 * 64 + c16 * 4);
    unsigned w1 = *(const unsigned*)(src + (size_t)e1 * 64 + c16 * 4);
    a4[0] += FP8D(w0, 0) + FP8D(w1, 0);
    a4[1] += FP8D(w0, 1) + FP8D(w1, 1);
    a4[2] += FP8D(w0, 2) + FP8D(w1, 2);
    a4[3] += FP8D(w0, 3) + FP8D(w1, 3);
    j += 8;
  }
  if (j + 4 <= s1) {
    int e0 = csr[j + sub];
    unsigned w0 = *(const unsigned*)(src + (size_t)e0 * 64 + c16 * 4);
    a4[0] += FP8D(w0, 0); a4[1] += FP8D(w0, 1);
    a4[2] += FP8D(w0, 2); a4[3] += FP8D(w0, 3);
    j += 4;
  }
  int rem = s1 - j;
  if (sub < rem) {
    int e0 = csr[j + sub];
    unsigned w0 = *(const unsigned*)(src + (size_t)e0 * 64 + c16 * 4);
    a4[0] += FP8D(w0, 0); a4[1] += FP8D(w0, 1);
    a4[2] += FP8D(w0, 2); a4[3] += FP8D(w0, 3);
  }
  #pragma unroll
  for (int c = 0; c < 4; c++) {
    a4[c] += __shfl_xor(a4[c], 16, 64);
    a4[c] += __shfl_xor(a4[c], 32, 64);
  }
  float acc = sub == 0 ? a4[0] : sub == 1 ? a4[1] : sub == 2 ? a4[2] : a4[3];
  int col = c16 * 4 + sub;               // lane→column permutation
  float val = acc * ISCALE_E_ * frcp(fmaxf((float)(s1 - s0), 1.0f));
  size_t idx = (size_t)r * 64 + col;
  out[idx] = __float2bfloat16(val);
  unsigned p = fp8_enc_pk(val * SCALE_1_, val * SCALE_1_);
  out8[idx] = (unsigned char)(p & 0xFF);
}

// ---------------- 3. fused layer-2 aggregation + attention (fp8 dword gather) ---------
__global__ __launch_bounds__(256) void agg2attn_kernel(
    const unsigned char* __restrict__ u18, const unsigned char* __restrict__ i18,
    const __hip_bfloat16* __restrict__ u1, const __hip_bfloat16* __restrict__ i1,
    const void* __restrict__ ue, const void* __restrict__ ie,
    const int* __restrict__ rowU, const int* __restrict__ rowI,
    const int* __restrict__ csrU, const int* __restrict__ csrI,
    const float* __restrict__ vecs, float* __restrict__ hu, float* __restrict__ hi,
    const float* __restrict__ flag) {
  int isf32 = *flag > 0.5f;
  int wv = threadIdx.x >> 6, lane = threadIdx.x & 63;
  int sub = lane >> 4, c16 = lane & 15;
  int side = blockIdx.x >= I_ / 4;          // 0: item rows, 1: user rows
  int blk = side ? blockIdx.x - I_ / 4 : blockIdx.x;
  int r = blk * 4 + wv;
  const int* row = side ? rowU : rowI;
  const int* csr = side ? csrU : csrI;
  const unsigned char* opp8 = side ? i18 : u18;
  const __hip_bfloat16* own1 = side ? u1 : i1;
  const void* base = side ? ue : ie;
  float* h = side ? hu : hi;
  int s0 = row[r], s1 = row[r + 1];
  float a4[4] = {0.f, 0.f, 0.f, 0.f};
  int j = s0;
  for (; j + 16 <= s1; j += 16) {        // 4 gathers in flight
    int e0 = csr[j + sub], e1 = csr[j + 4 + sub];
    int e2 = csr[j + 8 + sub], e3 = csr[j + 12 + sub];
    unsigned w0 = *(const unsigned*)(opp8 + (size_t)e0 * 64 + c16 * 4);
    unsigned w1 = *(const unsigned*)(opp8 + (size_t)e1 * 64 + c16 * 4);
    unsigned w2 = *(const unsigned*)(opp8 + (size_t)e2 * 64 + c16 * 4);
    unsigned w3 = *(const unsigned*)(opp8 + (size_t)e3 * 64 + c16 * 4);
    a4[0] += (FP8D(w0, 0) + FP8D(w1, 0)) + (FP8D(w2, 0) + FP8D(w3, 0));
    a4[1] += (FP8D(w0, 1) + FP8D(w1, 1)) + (FP8D(w2, 1) + FP8D(w3, 1));
    a4[2] += (FP8D(w0, 2) + FP8D(w1, 2)) + (FP8D(w2, 2) + FP8D(w3, 2));
    a4[3] += (FP8D(w0, 3) + FP8D(w1, 3)) + (FP8D(w2, 3) + FP8D(w3, 3));
  }
  if (j + 8 <= s1) {
    int e0 = csr[j + sub], e1 = csr[j + 4 + sub];
    unsigned w0 = *(const unsigned*)(opp8 + (size_t)e0 * 64 + c16 * 4);
    unsigned w1 = *(const unsigned*)(opp8 + (size_t)e1 * 64 + c16 * 4);
    a4[0] += FP8D(w0, 0) + FP8D(w1, 0);
    a4[1] += FP8D(w0, 1) + FP8D(w1, 1);
    a4[2] += FP8D(w0, 2) + FP8D(w1, 2);
    a4[3] += FP8D(w0, 3) + FP8D(w1, 3);
    j += 8;
  }
  if (j + 4 <= s1) {
    int e0 = csr[j + sub];
    unsigned w0 = *(const unsigned*)(opp8 + (size_t)e0 * 64 + c16 * 4);
    a4[0] += FP8D(w0, 0); a4[1] += FP8D(w0, 1);
    a4[2] += FP8D(w0, 2); a4[3] += FP8D(w0, 3);
    j += 4;
  }
  int rem = s1 - j;
  if (sub < rem) {
    int e0 = csr[j + sub];
    unsigned w0 = *(const unsigned*)(opp8 + (size_t)e0 * 64 + c16 * 4);
    a4[0] += FP8D(w0, 0); a4[1] += FP8D(w0, 1);
    a4[2] += FP8D(w0, 2); a4[3] += FP8D(w0, 3);
  }
  #pragma unroll
  for (int c = 0; c < 4; c++) {
    a4[c] += __shfl_xor(a4[c], 16, 64);
    a4[c] += __shfl_xor(a4[c], 32, 64);
  }
  float acc = sub == 0 ? a4[0] : sub == 1 ? a4[1] : sub == 2 ? a4[2] : a4[3];
  int col = c16 * 4 + sub;               // lane→column permutation
  size_t idx = (size_t)r * 64 + col;
  float t2 = acc * ISCALE_1_ * frcp(fmaxf((float)(s1 - s0), 1.0f));
  float t0 = ldf(base, idx, isf32);
  float t1 = b2f(own1[idx]);
  float w = vecs[col];   // Wa
  float p0 = t0 * w, p1 = t1 * w, p2 = t2 * w;
  #pragma unroll
  for (int off = 32; off; off >>= 1) {
    p0 += __shfl_xor(p0, off, 64);
    p1 += __shfl_xor(p1, off, 64);
    p2 += __shfl_xor(p2, off, 64);
  }
  float m = fmaxf(p0, fmaxf(p1, p2));
  float e0 = __expf(p0 - m), e1 = __expf(p1 - m), e2 = __expf(p2 - m);
  float inv = 1.0f / (e0 + e1 + e2);
  h[idx] = (t0 * e0 + t1 * e1 + t2 * e2) * inv;
}

// ---------------- 5. contrastive loss: slim epilogue MFMA Gram ----------
constexpr int XS_ = 72;                   // f16 row stride (144 B)
constexpr float SC_  = 2.6857914f;        // sqrt(5*log2(e))
constexpr float EPS_ = 1e-6f;
constexpr float LN2_ = 0.6931471805599453f;
__global__ __launch_bounds__(1024) void contrast_kernel(
    const float* __restrict__ hu, const float* __restrict__ an,
    float* __restrict__ loss_acc) {
  __shared__ __align__(16) _Float16 Xh[512 * XS_];  // 72 KB
  __shared__ float iN[512];
  int tid = threadIdx.x;
  int c = blockIdx.x;

  // phase 1: all 1024 threads, 2 threads per row (half-row each)
  {
    int rid = tid >> 1, half = tid & 1;   // rid 0..511
    int row = rid & 255;
    const float* r1 = (rid < 256 ? hu : an) + ((size_t)c * CB_ + row) * 64 + half * 32;
    float4 a4[8];
    float s1 = 0.f;
    #pragma unroll
    for (int t = 0; t < 8; t++) {
      a4[t] = ((const float4*)r1)[t];
      s1 += a4[t].x * a4[t].x + a4[t].y * a4[t].y + a4[t].z * a4[t].z + a4[t].w * a4[t].w;
    }
    s1 += __shfl_xor(s1, 1, 64);          // combine the two halves
    float inv = frcp(sqrtf(s1));
    if (half == 0) iN[rid] = inv;
    float sc = inv * SC_;
    #pragma unroll
    for (int t = 0; t < 4; t++) {
      f16x8 v;
      v[0] = (_Float16)(a4[2*t].x * sc);   v[1] = (_Float16)(a4[2*t].y * sc);
      v[2] = (_Float16)(a4[2*t].z * sc);   v[3] = (_Float16)(a4[2*t].w * sc);
      v[4] = (_Float16)(a4[2*t+1].x * sc); v[5] = (_Float16)(a4[2*t+1].y * sc);
      v[6] = (_Float16)(a4[2*t+1].z * sc); v[7] = (_Float16)(a4[2*t+1].w * sc);
      *(f16x8*)&Xh[rid * XS_ + half * 32 + t * 8] = v;
    }
  }
  __syncthreads();

  int l = tid & 63, wv = tid >> 6;       // wv 0..15
  int n = l & 15, q = l >> 4;
  int rb = wv * 32;
  f16x8 A[2][2];
  #pragma unroll
  for (int t = 0; t < 2; t++) {
    A[t][0] = *(const f16x8*)&Xh[(rb + t * 16 + n) * XS_ + q * 8];
    A[t][1] = *(const f16x8*)&Xh[(rb + t * 16 + n) * XS_ + 32 + q * 8];
  }
  float eNiR[2][4];
  #pragma unroll
  for (int t = 0; t < 2; t++)
    #pragma unroll
    for (int r = 0; r < 4; r++)
      eNiR[t][r] = EPS_ * iN[rb + t * 16 + q * 4 + r];
  float sums[2][4] = {{0,0,0,0},{0,0,0,0}};
  float labs2[2] = {0, 0};
  int selfn = q * 4;
  const floatx4 zero = {0.f, 0.f, 0.f, 0.f};
  for (int ct = 0; ct < 32; ct++) {
    f16x8 B0 = *(const f16x8*)&Xh[(ct * 16 + n) * XS_ + q * 8];
    f16x8 B1 = *(const f16x8*)&Xh[(ct * 16 + n) * XS_ + 32 + q * 8];
    float iNj = iN[ct * 16 + n];
    #pragma unroll
    for (int t = 0; t < 2; t++) {
      floatx4 acc = __builtin_amdgcn_mfma_f32_16x16x32_f16(A[t][0], B0, zero, 0, 0, 0);
      acc = __builtin_amdgcn_mfma_f32_16x16x32_f16(A[t][1], B1, acc, 0, 0, 0);
      int rtg = wv * 2 + t;
      if (ct == (rtg ^ 16)) {
        #pragma unroll
        for (int r = 0; r < 4; r++) {
          float G = acc[r];
          float u = eNiR[t][r] * iNj;
          float s2 = __builtin_fmaf(G, -u, G);
          sums[t][r] += fexp2(s2);
          if (n == selfn + r) labs2[t] += s2;
        }
      } else if (ct == rtg) {
        #pragma unroll
        for (int r = 0; r < 4; r++) {
          float G = acc[r];
          float u = eNiR[t][r] * iNj;
          float s2 = __builtin_fmaf(G, -u, G);
          float e = (n == selfn + r) ? 0.f : fexp2(s2);
          sums[t][r] += e;
        }
      } else {
        #pragma unroll
        for (int r = 0; r < 4; r++) {
          float G = acc[r];
          float u = eNiR[t][r] * iNj;
          float s2 = __builtin_fmaf(G, -u, G);
          sums[t][r] += fexp2(s2);
        }
      }
    }
  }
  #pragma unroll
  for (int off = 1; off <= 8; off <<= 1) {
    #pragma unroll
    for (int t = 0; t < 2; t++) {
      #pragma unroll
      for (int r = 0; r < 4; r++) sums[t][r] += __shfl_xor(sums[t][r], off, 64);
      labs2[t] += __shfl_xor(labs2[t], off, 64);
    }
  }
  float part = 0.f;
  if (n == 0) {
    #pragma unroll
    for (int t = 0; t < 2; t++) {
      float lt = 0.f;
      #pragma unroll
      for (int r = 0; r < 4; r++) lt += __logf(sums[t][r]);
      part += lt - labs2[t] * LN2_;
    }
  }
  #pragma unroll
  for (int off = 1; off < 64; off <<= 1) part += __shfl_xor(part, off, 64);
  if (l == 0) atomicAdd(loss_acc, part);
}

// ---------------- 6. scores: 4 edges per wave (16-lane groups, float4 rows) ----------
__global__ __launch_bounds__(256) void score_kernel(
    const float* __restrict__ hu, const float* __restrict__ hi,
    const int* __restrict__ pu, const int* __restrict__ pi,
    const int* __restrict__ nu, const int* __restrict__ ni,
    void* __restrict__ out, const float* __restrict__ flag) {
  int isf32 = *flag > 0.5f;
  int lane = threadIdx.x & 63;
  int g = lane >> 4, c = lane & 15;     // group 0..3, lane-in-group
  int gw = blockIdx.x * 4 + (threadIdx.x >> 6);
  int w = gw * 4 + g;                    // edge id, < 2*EP_
  int uu, ii;
  if (w < EP_) { uu = pu[w]; ii = pi[w]; }
  else         { uu = nu[w - EP_]; ii = ni[w - EP_]; }
  float4 a = *(const float4*)(hu + (size_t)uu * 64 + c * 4);
  float4 b = *(const float4*)(hi + (size_t)ii * 64 + c * 4);
  float p = a.x * b.x + a.y * b.y + a.z * b.z + a.w * b.w;
  #pragma unroll
  for (int off = 1; off < 16; off <<= 1) p += __shfl_xor(p, off, 64);
  if (c == 0) {
    if (isf32) ((float*)out)[w] = p;
    else       ((__hip_bfloat16*)out)[w] = __float2bfloat16(p);
  }
}

__global__ void finalize_kernel(const float* __restrict__ loss_acc,
                                void* __restrict__ out,
                                const float* __restrict__ flag) {
  float v = loss_acc[0] * (1.0f / (float)(2 * CB_ * NCHUNK_));
  if (*flag > 0.5f) ((float*)out)[2 * EP_] = v;
  else              ((__hip_bfloat16*)out)[2 * EP_] = __float2bfloat16(v);
}

// ---------------- launch ----------------
extern "C" void kernel_launch(void* const* d_in, const int* in_sizes, int n_in,
                              void* d_out, int out_size, void* d_ws, size_t ws_size,
                              hipStream_t stream) {
  const void* ue  = d_in[0];
  const void* ie  = d_in[1];
  const void* W   = d_in[2];
  const void* a   = d_in[3];
  const void* WU  = d_in[4];
  const void* aU  = d_in[5];
  const void* cw  = d_in[6];
  const int* rs  = (const int*)d_in[7];
  const int* rd  = (const int*)d_in[8];
  const int* pu  = (const int*)d_in[9];
  const int* pi  = (const int*)d_in[10];
  const int* nu  = (const int*)d_in[11];
  const int* ni  = (const int*)d_in[12];
  const int* nbr = (const int*)d_in[13];

  float* wsf  = (float*)d_ws;
  int*   wsi  = (int*)d_ws;
  float* loss = wsf + OFF_LOSS;
  float* flag = wsf + OFF_FLAG;
  int* curU   = wsi + OFF_CURU;
  int* curI   = wsi + OFF_CURI;
  float* vecs = wsf + OFF_VEC;
  int* rowU   = wsi + OFF_ROWU;
  int* rowI   = wsi + OFF_ROWI;
  int* csrU   = wsi + OFF_CSRU;
  int* csrI   = wsi + OFF_CSRI;
  __hip_bfloat16* u1 = (__hip_bfloat16*)(wsf + OFF_U1);
  __hip_bfloat16* i1 = (__hip_bfloat16*)(wsf + OFF_I1);
  float* hu   = wsf + OFF_HU;
  float* hi   = wsf + OFF_HI;
  float* anc  = wsf + OFF_ANC;
  unsigned char* ue8 = (unsigned char*)(wsf + OFF_UE8);
  unsigned char* ie8 = (unsigned char*)(wsf + OFF_IE8);
  unsigned char* u18 = (unsigned char*)(wsf + OFF_U18);
  unsigned char* i18 = (unsigned char*)(wsf + OFF_I18);
  unsigned* bufU = (unsigned*)(wsf + OFF_HU);
  unsigned* bufI = (unsigned*)(wsf + OFF_HI);

  // prep also zeroes loss + bucket counters (memset launch removed)
  prep_kernel<<<1, 256, 0, stream>>>((const unsigned short*)ue, W, a, WU, aU,
                                     vecs, flag, wsf);

  // fused: CSR Phase A + anchor + fp8 convert (all independent)
  // TILE_=1024 -> 14.7KB LDS -> 8 blocks/CU (100% occupancy ceiling)
  fusedA_kernel<<<NBA_ + NANC_ + NCVT_, 256, 0, stream>>>(
      rs, rd, bufU, bufI, curU, curI, ue, ie, WU, cw, vecs, nbr, anc, ue8, ie8, flag);

  // Phase B with per-block local scan
  bucketB_kernel<<<2 * NBK_, 256, 0, stream>>>(bufU, bufI, curU, curI,
                                               rowU, rowI, csrU, csrI);

  // fused layer-1 aggregation (fp8 dword gather, both sides)
  agg1_kernel<<<(I_ + U_) / 4, 256, 0, stream>>>(ue8, ie8, rowU, rowI, csrU, csrI,
                                                 u1, i1, u18, i18);
  // fused layer-2 aggregation + attention (fp8 dword gather, both sides)
  agg2attn_kernel<<<(I_ + U_) / 4, 256, 0, stream>>>(u18, i18, u1, i1, ue, ie,
                                                     rowU, rowI, csrU, csrI,
                                                     vecs, hu, hi, flag);

  // contrastive loss (dedicated CUs, 1024 threads)
  contrast_kernel<<<NCHUNK_, 1024, 0, stream>>>(hu, anc, loss);

  // scores (256-thr blocks, 4 edges/wave, high residency)
  score_kernel<<<NSCB_, 256, 0, stream>>>(hu, hi, pu, pi, nu, ni, d_out, flag);
  finalize_kernel<<<1, 1, 0, stream>>>(loss, d_out, flag);
}

// Round 6
// 340.054 us; speedup vs baseline: 1.0024x; 1.0024x over previous
//
#include <hip/hip_runtime.h>
#include <hip/hip_bf16.h>

// ---------------- problem constants ----------------
constexpr int U_  = 51200;
constexpr int I_  = 25600;
constexpr int E_  = 1000000;
constexpr int EP_ = 100000;
constexpr int CB_ = 256;                 // contrastive chunk size
constexpr int NCHUNK_ = U_ / CB_;        // 200
constexpr size_t UD_ = (size_t)U_ * 64;
constexpr size_t ID_ = (size_t)I_ * 64;
constexpr int NBK_ = 200;                // buckets per side
constexpr int CAP_ = 8192;               // record slots per bucket
constexpr int TILE_ = 4096;              // edges per Phase-A block (amortizes hist/scan, big scatter chunks)
constexpr int NBA_ = (E_ + TILE_ - 1) / TILE_;  // 245
constexpr int NANC_ = U_ / 16;           // 3200 anchor blocks
constexpr int NCVT_ = (int)((UD_ + ID_) / (8 * 256));  // 2400 convert blocks (8 elem/thread)
constexpr int NSCB_ = (2 * EP_) / 16;    // 12500 score blocks (16 edges/block)

// fp8 scaling (values sit in e4m3 sweet range)
constexpr float SCALE_E_  = 16.f;   // raw embeddings ~0.1
constexpr float ISCALE_E_ = 1.f / 16.f;
constexpr float SCALE_1_  = 64.f;   // layer-1 aggregates ~0.02
constexpr float ISCALE_1_ = 1.f / 64.f;

// ---------------- workspace layout (4-byte element offsets) ----------------
constexpr size_t OFF_LOSS  = 0;
constexpr size_t OFF_FLAG  = 1;
constexpr size_t OFF_CURU  = 8;                      // 200 ints
constexpr size_t OFF_CURI  = 208;                    // 200 ints
constexpr size_t OFF_VEC   = 448;                    // 192 floats
constexpr size_t OFF_ROWU  = 1088;                   // U_+1
constexpr size_t OFF_ROWI  = ((OFF_ROWU + U_ + 1 + 63) / 64) * 64;   // I_+1
constexpr size_t OFF_CSRU  = ((OFF_ROWI + I_ + 1 + 63) / 64) * 64;   // E_
constexpr size_t OFF_CSRI  = OFF_CSRU + E_;          // E_
constexpr size_t OFF_U1    = ((OFF_CSRI + E_ + 63) / 64) * 64;       // UD_ (bf16)
constexpr size_t OFF_I1    = OFF_U1 + UD_;
constexpr size_t OFF_HU    = OFF_I1 + ID_;           // bufU aliases
constexpr size_t OFF_HI    = OFF_HU + UD_;           // bufI aliases
constexpr size_t OFF_ANC   = OFF_HI + ID_;
constexpr size_t OFF_UE8   = OFF_ANC + UD_;          // UD_ bytes (fp8)
constexpr size_t OFF_IE8   = OFF_UE8 + UD_ / 4;
constexpr size_t OFF_U18   = OFF_IE8 + ID_ / 4;
constexpr size_t OFF_I18   = OFF_U18 + UD_ / 4;
// total ≈ 65.6 MB

#define DEVI static __device__ __forceinline__

typedef _Float16 h2v __attribute__((ext_vector_type(2)));
typedef _Float16 f16x8 __attribute__((ext_vector_type(8)));
typedef float floatx4 __attribute__((ext_vector_type(4)));
typedef unsigned short u16x8 __attribute__((ext_vector_type(8)));

DEVI float b2f(__hip_bfloat16 x) { return __bfloat162float(x); }

DEVI float bfb2f(unsigned short b) {
  unsigned u = ((unsigned)b) << 16; float f; __builtin_memcpy(&f, &u, 4); return f;
}

DEVI float ldf(const void* p, size_t i, int isf32) {
  if (isf32) return ((const float*)p)[i];
  return b2f(((const __hip_bfloat16*)p)[i]);
}

DEVI float frcp(float x) { return __builtin_amdgcn_rcpf(x); }

DEVI float fexp2(float x) {
#if __has_builtin(__builtin_amdgcn_exp2f)
  return __builtin_amdgcn_exp2f(x);
#else
  return exp2f(x);
#endif
}

// fp8 e4m3 (OCP) decode/encode
DEVI float fp8_dec(unsigned v) {
#if __has_builtin(__builtin_amdgcn_cvt_f32_fp8)
  return __builtin_amdgcn_cvt_f32_fp8(v, 0);
#else
  unsigned b = v & 0xFF;
  if (!(b & 0x78)) return 0.f;  // flush subnormals (negligible at our scales)
  unsigned short h = (unsigned short)(((b & 0x80) << 8) | (((b & 0x7f) + (8 << 3)) << 7));
  _Float16 hf; __builtin_memcpy(&hf, &h, 2);
  return (float)hf;
#endif
}

// decode byte `s` (compile-time literal) of dword w
#if __has_builtin(__builtin_amdgcn_cvt_f32_fp8)
#define FP8D(w, s) __builtin_amdgcn_cvt_f32_fp8((w), (s))
#else
#define FP8D(w, s) fp8_dec(((w) >> (8 * (s))) & 0xFF)
#endif

DEVI unsigned fp8_enc_pk(float a, float b) {
#if __has_builtin(__builtin_amdgcn_cvt_pk_fp8_f32)
  return __builtin_amdgcn_cvt_pk_fp8_f32(a, b, 0u, false);
#else
  auto enc1 = [](float f) -> unsigned {
    _Float16 hf = (_Float16)f; unsigned short hb; __builtin_memcpy(&hb, &hf, 2);
    int s = hb >> 15, e = (hb >> 10) & 31, m = hb & 1023;
    int e8 = e - 15 + 7;
    int m3 = (m + ((1 << 6) + ((m >> 7) & 1))) >> 7;
    if (m3 > 7) { m3 = 0; e8++; }
    if (e8 <= 0) return (unsigned)(s << 7);
    if (e8 > 15) { e8 = 15; m3 = 6; }
    return (unsigned)((s << 7) | (e8 << 3) | m3);
  };
  return enc1(a) | (enc1(b) << 8);
#endif
}

DEVI int waveInclScan(int v, int lane) {
  #pragma unroll
  for (int off = 1; off < 64; off <<= 1) {
    int t = __shfl_up(v, off, 64);
    if (lane >= off) v += t;
  }
  return v;
}

// ---------------- 0. prep (also zeroes loss + bucket counters) ----------------
__global__ void prep_kernel(const unsigned short* __restrict__ ueu,
                            const void* __restrict__ W, const void* __restrict__ a,
                            const void* __restrict__ WU, const void* __restrict__ aU,
                            float* __restrict__ vecs, float* __restrict__ flag,
                            float* __restrict__ ws0) {
  int tid = threadIdx.x;
  for (int i = tid; i < 408; i += 256)
    if (i == 0 || i >= 8) ws0[i] = 0.f;
  if (tid < 64) {
    int cnt = 0;
    for (int i = 0; i < 256; i++) {
      int e = (ueu[i] >> 7) & 0xFF;
      if (e >= 130) cnt++;
    }
    int isf32 = (cnt >= 8);
    if (tid == 0) *flag = isf32 ? 1.0f : 0.0f;
    int d = tid;
    float s = 0.f, t1 = 0.f, t2 = 0.f;
    for (int e = 0; e < 64; e++) {
      s += ldf(W, d * 64 + e, isf32) * ldf(a, e, isf32);
      float wue = ldf(WU, d * 64 + e, isf32);
      t1 += wue * ldf(aU, e, isf32);
      t2 += wue * ldf(aU, 64 + e, isf32);
    }
    vecs[d] = s;
    vecs[64 + d] = t1;
    vecs[128 + d] = t2;
  }
}

// ---------------- fused A: anchor + bucketA + fp8-convert (LPT order) -------------
struct BktSmem {            // ~39.4 KB at TILE_=4096
  int histU[NBK_], histI[NBK_];
  int loffU[NBK_ + 1], loffI[NBK_ + 1];
  int cbU[NBK_], cbI[NBK_];
  int lcU[NBK_], lcI[NBK_];
  int wsU[4], wsI[4];
  unsigned recsU[TILE_], recsI[TILE_];
};
constexpr int WS_ = 72;
struct AncSmem {            // ~11.6 KB
  _Float16 WUt[64 * WS_];
  _Float16 mixS[16 * WS_];
  float invSe[16];
  int nbrS[128];
};
constexpr size_t FSA_SMEM = sizeof(BktSmem) > sizeof(AncSmem) ? sizeof(BktSmem) : sizeof(AncSmem);

DEVI void bucketA_body(char* smemRaw, int blk,
    const int* __restrict__ rs, const int* __restrict__ rd,
    unsigned* __restrict__ bufU, unsigned* __restrict__ bufI,
    int* __restrict__ curU, int* __restrict__ curI) {
  BktSmem& S = *(BktSmem*)smemRaw;
  int tid = threadIdx.x;
  int base = blk * TILE_;
  for (int i = tid; i < NBK_; i += 256) { S.histU[i] = 0; S.histI[i] = 0; }
  __syncthreads();
  int ss[16], dd[16];
  #pragma unroll
  for (int t = 0; t < 16; t++) {
    int e = base + t * 256 + tid;
    bool v = e < E_;
    ss[t] = v ? rs[e] : -1;
    dd[t] = v ? rd[e] : 0;
    if (v) {
      atomicAdd(&S.histU[ss[t] >> 8], 1);
      atomicAdd(&S.histI[dd[t] >> 7], 1);
    }
  }
  __syncthreads();
  if (tid < NBK_) {
    int cU = S.histU[tid];
    S.cbU[tid] = tid * CAP_ + (cU ? atomicAdd(&curU[tid], cU) : 0);
    int cI = S.histI[tid];
    S.cbI[tid] = tid * CAP_ + (cI ? atomicAdd(&curI[tid], cI) : 0);
  }
  int lane = tid & 63, wv = tid >> 6;
  int cvU = (tid < NBK_) ? S.histU[tid] : 0;
  int cvI = (tid < NBK_) ? S.histI[tid] : 0;
  int inU = waveInclScan(cvU, lane);
  int inI = waveInclScan(cvI, lane);
  if (lane == 63) { S.wsU[wv] = inU; S.wsI[wv] = inI; }
  __syncthreads();
  int woU = 0, woI = 0;
  for (int w = 0; w < wv; w++) { woU += S.wsU[w]; woI += S.wsI[w]; }
  if (tid < NBK_) {
    S.loffU[tid] = woU + inU - cvU;
    S.loffI[tid] = woI + inI - cvI;
  }
  if (tid == NBK_ - 1) {
    S.loffU[NBK_] = woU + inU;
    S.loffI[NBK_] = woI + inI;
  }
  __syncthreads();
  if (tid < NBK_) { S.lcU[tid] = S.loffU[tid]; S.lcI[tid] = S.loffI[tid]; }
  __syncthreads();
  #pragma unroll
  for (int t = 0; t < 16; t++) {
    if (ss[t] >= 0) {
      int b = ss[t] >> 8;
      int p = atomicAdd(&S.lcU[b], 1);
      S.recsU[p] = ((unsigned)(ss[t] & 255) << 17) | (unsigned)dd[t];
      b = dd[t] >> 7;
      p = atomicAdd(&S.lcI[b], 1);
      S.recsI[p] = ((unsigned)(dd[t] & 127) << 17) | (unsigned)ss[t];
    }
  }
  __syncthreads();
  int totU = S.loffU[NBK_];
  for (int p = tid; p < totU; p += 256) {
    int lo = 0, hi = NBK_;
    while (hi - lo > 1) { int mid = (lo + hi) >> 1; if (S.loffU[mid] <= p) lo = mid; else hi = mid; }
    bufU[S.cbU[lo] + (p - S.loffU[lo])] = S.recsU[p];
  }
  int totI = S.loffI[NBK_];
  for (int p = tid; p < totI; p += 256) {
    int lo = 0, hi = NBK_;
    while (hi - lo > 1) { int mid = (lo + hi) >> 1; if (S.loffI[mid] <= p) lo = mid; else hi = mid; }
    bufI[S.cbI[lo] + (p - S.loffI[lo])] = S.recsI[p];
  }
}

// anchor: FFT-filter + neighbor attention (distributed multi-value reductions)
DEVI void anchor_body(char* smemRaw, int blk,
    const void* __restrict__ ue, const void* __restrict__ WU,
    const void* __restrict__ cw, const float* __restrict__ vecs,
    const int* __restrict__ nbr, float* __restrict__ out, int isf32) {
  AncSmem& S = *(AncSmem*)smemRaw;
  int tid = threadIdx.x;
  int wv = tid >> 6, lane = tid & 63;
  int ublk = blk * 16;

  #pragma unroll
  for (int it = 0; it < 16; it++) {
    int k = it * 4 + wv;
    S.WUt[lane * WS_ + k] = (_Float16)ldf(WU, (size_t)k * 64 + lane, isf32);
  }
  if (tid < 128) S.nbrS[tid] = nbr[ublk * 8 + tid];
  __syncthreads();

  float cw0 = ldf(cw, (0 * 64 + lane) * 2, isf32);
  float w1r = ldf(cw, (1 * 64 + lane) * 2, isf32), w1i = ldf(cw, (1 * 64 + lane) * 2 + 1, isf32);
  float w2r = ldf(cw, (2 * 64 + lane) * 2, isf32), w2i = ldf(cw, (2 * 64 + lane) * 2 + 1, isf32);
  float w3r = ldf(cw, (3 * 64 + lane) * 2, isf32), w3i = ldf(cw, (3 * 64 + lane) * 2 + 1, isf32);
  float cw4 = ldf(cw, (4 * 64 + lane) * 2, isf32);
  float v1 = vecs[64 + lane], v2 = vecs[128 + lane];
  const float c1 = 0.70710678118654752440f;

  bool b3 = (lane & 8) != 0, b4 = (lane & 16) != 0, b5 = (lane & 32) != 0;

  // q for the wave's 4 users: distributed reduce over lane-bit-{4,5}
  float qv0 = ldf(ue, (size_t)(ublk + wv * 4 + 0) * 64 + lane, isf32) * v2;
  float qv1 = ldf(ue, (size_t)(ublk + wv * 4 + 1) * 64 + lane, isf32) * v2;
  float qv2 = ldf(ue, (size_t)(ublk + wv * 4 + 2) * 64 + lane, isf32) * v2;
  float qv3 = ldf(ue, (size_t)(ublk + wv * 4 + 3) * 64 + lane, isf32) * v2;
  qv0 += __shfl_xor(qv0, 16, 64); qv0 += __shfl_xor(qv0, 32, 64);
  qv1 += __shfl_xor(qv1, 16, 64); qv1 += __shfl_xor(qv1, 32, 64);
  qv2 += __shfl_xor(qv2, 16, 64); qv2 += __shfl_xor(qv2, 32, 64);
  qv3 += __shfl_xor(qv3, 16, 64); qv3 += __shfl_xor(qv3, 32, 64);
  float qs0 = b4 ? qv1 : qv0;
  float qs1 = b4 ? qv3 : qv2;
  float qw = b5 ? qs1 : qs0;
  qw += __shfl_xor(qw, 1, 64); qw += __shfl_xor(qw, 2, 64);
  qw += __shfl_xor(qw, 4, 64); qw += __shfl_xor(qw, 8, 64);
  // lane l now holds Q[l>>4]

  float xc[8], xn[8];
  #pragma unroll
  for (int k = 0; k < 8; k++)
    xc[k] = ldf(ue, (size_t)S.nbrS[wv * 32 + k] * 64 + lane, isf32);

  for (int u4 = 0; u4 < 4; u4++) {
    int uL = wv * 4 + u4;
    if (u4 < 3) {
      #pragma unroll
      for (int k = 0; k < 8; k++)
        xn[k] = ldf(ue, (size_t)S.nbrS[wv * 32 + (u4 + 1) * 8 + k] * 64 + lane, isf32);
    }
    float sA = xc[1] - xc[3] - xc[5] + xc[7];
    float sB = xc[1] + xc[3] - xc[5] - xc[7];
    float ev = (xc[0] + xc[4]) + (xc[2] + xc[6]);
    float od = (xc[1] + xc[5]) + (xc[3] + xc[7]);
    float d04 = xc[0] - xc[4], d26 = xc[2] - xc[6];
    float X0r = ev + od;
    float X1r = d04 + c1 * sA;
    float X1i = -d26 - c1 * sB;
    float X2r = (xc[0] + xc[4]) - (xc[2] + xc[6]);
    float X2i = -(xc[1] - xc[3] + xc[5] - xc[7]);
    float X3r = d04 - c1 * sA;
    float X3i = d26 - c1 * sB;
    float X4r = ev - od;
    float Zr0 = X0r * cw0;
    float Zr1 = X1r * w1r - X1i * w1i, Zi1 = X1r * w1i + X1i * w1r;
    float Zr2 = X2r * w2r - X2i * w2i, Zi2 = X2r * w2i + X2i * w2r;
    float Zr3 = X3r * w3r - X3i * w3i, Zi3 = X3r * w3i + X3i * w3r;
    float Zr4 = X4r * cw4;
    float eP = Zr0 + Zr4, eM = Zr0 - Zr4;
    float t1 = c1 * (Zr1 - Zr3), t2 = c1 * (Zi1 + Zi3);
    float y[8];
    y[0] = eP + 2.f * (Zr1 + Zr2 + Zr3);
    y[1] = eM + 2.f * (t1 - t2 - Zi2);
    y[2] = eP + 2.f * (-Zi1 - Zr2 + Zi3);
    y[3] = eM + 2.f * (-t1 - t2 + Zi2);
    y[4] = eP + 2.f * (-Zr1 + Zr2 - Zr3);
    y[5] = eM + 2.f * (-t1 + t2 - Zi2);
    y[6] = eP + 2.f * (Zi1 - Zr2 - Zi3);
    y[7] = eM + 2.f * (t1 + t2 + Zi2);
    #pragma unroll
    for (int k = 0; k < 8; k++) y[k] *= 0.125f;

    // 8 dot-products vs v1: distributed reduce
    float p0 = y[0] * v1, p1 = y[1] * v1, p2 = y[2] * v1, p3 = y[3] * v1;
    float p4 = y[4] * v1, p5 = y[5] * v1, p6 = y[6] * v1, p7 = y[7] * v1;
    p0 += __shfl_xor(p0, 8, 64);  p0 += __shfl_xor(p0, 16, 64); p0 += __shfl_xor(p0, 32, 64);
    p1 += __shfl_xor(p1, 8, 64);  p1 += __shfl_xor(p1, 16, 64); p1 += __shfl_xor(p1, 32, 64);
    p2 += __shfl_xor(p2, 8, 64);  p2 += __shfl_xor(p2, 16, 64); p2 += __shfl_xor(p2, 32, 64);
    p3 += __shfl_xor(p3, 8, 64);  p3 += __shfl_xor(p3, 16, 64); p3 += __shfl_xor(p3, 32, 64);
    p4 += __shfl_xor(p4, 8, 64);  p4 += __shfl_xor(p4, 16, 64); p4 += __shfl_xor(p4, 32, 64);
    p5 += __shfl_xor(p5, 8, 64);  p5 += __shfl_xor(p5, 16, 64); p5 += __shfl_xor(p5, 32, 64);
    p6 += __shfl_xor(p6, 8, 64);  p6 += __shfl_xor(p6, 16, 64); p6 += __shfl_xor(p6, 32, 64);
    p7 += __shfl_xor(p7, 8, 64);  p7 += __shfl_xor(p7, 16, 64); p7 += __shfl_xor(p7, 32, 64);
    float a0 = b3 ? p1 : p0;
    float a1 = b3 ? p3 : p2;
    float a2 = b3 ? p5 : p4;
    float a3 = b3 ? p7 : p6;
    float c0 = b4 ? a1 : a0;
    float c1s = b4 ? a3 : a2;
    float w = b5 ? c1s : c0;
    w += __shfl_xor(w, 1, 64); w += __shfl_xor(w, 2, 64); w += __shfl_xor(w, 4, 64);
    // lane l holds EK[l>>3]

    float qu = __shfl(qw, u4 * 16, 64);
    float v = w + qu;
    v = v > 0.f ? v : 0.1f * v;              // LeakyReLU(0.1)
    float m = v;
    m = fmaxf(m, __shfl_xor(m, 8, 64));
    m = fmaxf(m, __shfl_xor(m, 16, 64));
    m = fmaxf(m, __shfl_xor(m, 32, 64));
    float wexp = __expf(v - m);
    float se = wexp;
    se += __shfl_xor(se, 8, 64); se += __shfl_xor(se, 16, 64); se += __shfl_xor(se, 32, 64);
    float mix = 0.f;
    #pragma unroll
    for (int k = 0; k < 8; k++)
      mix += __shfl(wexp, k * 8, 64) * y[k];
    S.mixS[uL * WS_ + lane] = (_Float16)mix;
    if (lane == 0) S.invSe[uL] = frcp(se);
    #pragma unroll
    for (int k = 0; k < 8; k++) xc[k] = xn[k];
  }
  __syncthreads();

  int n = lane & 15, qd = lane >> 4;
  f16x8 A0 = *(const f16x8*)&S.mixS[(lane & 15) * WS_ + qd * 8];
  f16x8 A1 = *(const f16x8*)&S.mixS[(lane & 15) * WS_ + 32 + qd * 8];
  f16x8 B0 = *(const f16x8*)&S.WUt[(wv * 16 + n) * WS_ + qd * 8];
  f16x8 B1 = *(const f16x8*)&S.WUt[(wv * 16 + n) * WS_ + 32 + qd * 8];
  const floatx4 zero = {0.f, 0.f, 0.f, 0.f};
  floatx4 acc = __builtin_amdgcn_mfma_f32_16x16x32_f16(A0, B0, zero, 0, 0, 0);
  acc = __builtin_amdgcn_mfma_f32_16x16x32_f16(A1, B1, acc, 0, 0, 0);
  #pragma unroll
  for (int r = 0; r < 4; r++) {
    int m = qd * 4 + r;
    out[(size_t)(ublk + m) * 64 + wv * 16 + n] = acc[r] * S.invSe[m];
  }
}

// 8 elements per thread, vector loads (fp32: 2×float4, bf16: 1×ushort8)
DEVI void convert_body(int blk, const void* __restrict__ ue, const void* __restrict__ ie,
                       unsigned char* __restrict__ ue8, unsigned char* __restrict__ ie8,
                       int isf32) {
  size_t t = (size_t)blk * 256 + threadIdx.x;   // 8-element group index
  const void* src; unsigned* dst; size_t o;
  if (t < UD_ / 8) { src = ue; dst = (unsigned*)ue8; o = t; }
  else             { src = ie; dst = (unsigned*)ie8; o = t - UD_ / 8; }
  float v[8];
  if (isf32) {
    float4 f0 = ((const float4*)src)[2 * o];
    float4 f1 = ((const float4*)src)[2 * o + 1];
    v[0] = f0.x; v[1] = f0.y; v[2] = f0.z; v[3] = f0.w;
    v[4] = f1.x; v[5] = f1.y; v[6] = f1.z; v[7] = f1.w;
  } else {
    u16x8 h = ((const u16x8*)src)[o];
    #pragma unroll
    for (int i = 0; i < 8; i++) v[i] = bfb2f(h[i]);
  }
  unsigned lo = fp8_enc_pk(v[0] * SCALE_E_, v[1] * SCALE_E_) |
                (fp8_enc_pk(v[2] * SCALE_E_, v[3] * SCALE_E_) << 16);
  unsigned hi = fp8_enc_pk(v[4] * SCALE_E_, v[5] * SCALE_E_) |
                (fp8_enc_pk(v[6] * SCALE_E_, v[7] * SCALE_E_) << 16);
  dst[2 * o]     = lo;
  dst[2 * o + 1] = hi;
}

__global__ __launch_bounds__(256) void fusedA_kernel(
    const int* __restrict__ rs, const int* __restrict__ rd,
    unsigned* __restrict__ bufU, unsigned* __restrict__ bufI,
    int* __restrict__ curU, int* __restrict__ curI,
    const void* __restrict__ ue, const void* __restrict__ ie,
    const void* __restrict__ WU, const void* __restrict__ cw,
    const float* __restrict__ vecs, const int* __restrict__ nbr,
    float* __restrict__ anc, unsigned char* __restrict__ ue8,
    unsigned char* __restrict__ ie8, const float* __restrict__ flag) {
  __shared__ __align__(16) char smem[FSA_SMEM];
  // LPT order: long anchor blocks first, tiny convert blocks fill the tail
  if (blockIdx.x < NANC_) {
    anchor_body(smem, blockIdx.x, ue, WU, cw, vecs, nbr, anc, *flag > 0.5f);
  } else if (blockIdx.x < NANC_ + NBA_) {
    bucketA_body(smem, blockIdx.x - NANC_, rs, rd, bufU, bufI, curU, curI);
  } else {
    convert_body(blockIdx.x - NANC_ - NBA_, ue, ie, ue8, ie8, *flag > 0.5f);
  }
}

// ---------------- 1c. Phase B (with per-block local bucket scan) ----------------
struct BktBSmem {
  int stage[CAP_];
  int cntk[256], offk[256];
  int exclS[256];
  int wsum[4], wsum2[4];
};

__global__ __launch_bounds__(256) void bucketB_kernel(
    const unsigned* __restrict__ bufU, const unsigned* __restrict__ bufI,
    const int* __restrict__ curU, const int* __restrict__ curI,
    int* __restrict__ rowU, int* __restrict__ rowI,
    int* __restrict__ csrU, int* __restrict__ csrI) {
  __shared__ __align__(16) BktBSmem S;
  int tid = threadIdx.x, b = blockIdx.x;
  int side = b >= NBK_;
  int bb = side ? b - NBK_ : b;
  const unsigned* src = (side ? bufI : bufU) + (size_t)bb * CAP_;
  const int* cur = side ? curI : curU;
  int total = cur[bb];
  int kpb   = side ? 128 : 256;
  int* rowptr = side ? rowI : rowU;
  int* csr    = side ? csrI : csrU;
  if (b == 0 && tid == 0) { rowU[U_] = E_; rowI[I_] = E_; }
  int lane = tid & 63, wv = tid >> 6;
  // local exclusive scan of cur[0..NBK_) -> gbase
  {
    int v = (tid < NBK_) ? cur[tid] : 0;
    int incl = waveInclScan(v, lane);
    if (lane == 63) S.wsum2[wv] = incl;
    S.cntk[tid] = 0;
    __syncthreads();
    int off = 0;
    for (int w = 0; w < wv; w++) off += S.wsum2[w];
    if (tid < NBK_) S.exclS[tid] = off + incl - v;
    __syncthreads();
  }
  int gbase = S.exclS[bb];
  for (int r = tid; r < total; r += 256) atomicAdd(&S.cntk[src[r] >> 17], 1);
  __syncthreads();
  int cv = (tid < kpb) ? S.cntk[tid] : 0;
  int incl = waveInclScan(cv, lane);
  if (lane == 63) S.wsum[wv] = incl;
  __syncthreads();
  int wvoff = 0;
  for (int w = 0; w < wv; w++) wvoff += S.wsum[w];
  int excl = wvoff + incl - cv;
  if (tid < kpb) {
    S.offk[tid] = excl;
    rowptr[bb * kpb + tid] = gbase + excl;
  }
  __syncthreads();
  for (int r = tid; r < total; r += 256) {
    unsigned rec = src[r];
    int slot = atomicAdd(&S.offk[rec >> 17], 1);
    if (slot < CAP_) S.stage[slot] = (int)(rec & 0x1FFFFu);
  }
  __syncthreads();
  for (int s = tid; s < total; s += 256) csr[gbase + s] = S.stage[s];
}

// ---------------- 2. fused layer-1 aggregation (fp8 dword gather, bf16+fp8 out) -------
// lane = sub*16 + c16; each lane loads one dword (4 fp8 cols) of edge csr[j+sub]
__global__ __launch_bounds__(256) void agg1_kernel(
    const unsigned char* __restrict__ ue8, const unsigned char* __restrict__ ie8,
    const int* __restrict__ rowU, const int* __restrict__ rowI,
    const int* __restrict__ csrU, const int* __restrict__ csrI,
    __hip_bfloat16* __restrict__ u1, __hip_bfloat16* __restrict__ i1,
    unsigned char* __restrict__ u18, unsigned char* __restrict__ i18) {
  int wv = threadIdx.x >> 6, lane = threadIdx.x & 63;
  int sub = lane >> 4, c16 = lane & 15;
  int side = blockIdx.x >= I_ / 4;          // 0: item rows (gather ue8), 1: user rows
  int blk = side ? blockIdx.x - I_ / 4 : blockIdx.x;
  int r = blk * 4 + wv;
  const int* row = side ? rowU : rowI;
  const int* csr = side ? csrU : csrI;
  const unsigned char* src = side ? ie8 : ue8;
  __hip_bfloat16* out = side ? u1 : i1;
  unsigned char* out8 = side ? u18 : i18;
  int s0 = row[r], s1 = row[r + 1];
  float a4[4] = {0.f, 0.f, 0.f, 0.f};
  int j = s0;
  for (; j + 16 <= s1; j += 16) {        // 4 gathers in flight
    int e0 = csr[j + sub], e1 = csr[j + 4 + sub];
    int e2 = csr[j + 8 + sub], e3 = csr[j + 12 + sub];
    unsigned w0 = *(const unsigned*)(src + (size_t)e0 * 64 + c16 * 4);
    unsigned w1 = *(const unsigned*)(src + (size_t)e1 * 64 + c16 * 4);
    unsigned w2 = *(const unsigned*)(src + (size_t)e2 * 64 + c16 * 4);
    unsigned w3 = *(const unsigned*)(src + (size_t)e3 * 64 + c16 * 4);
    a4[0] += (FP8D(w0, 0) + FP8D(w1, 0)) + (FP8D(w2, 0) + FP8D(w3, 0));
    a4[1] += (FP8D(w0, 1) + FP8D(w1, 1)) + (FP8D(w2, 1) + FP8D(w3, 1));
    a4[2] += (FP8D(w0, 2) + FP8D(w1, 2)) + (FP8D(w2, 2) + FP8D(w3, 2));
    a4[3] += (FP8D(w0, 3) + FP8D(w1, 3)) + (FP8D(w2, 3) + FP8D(w3, 3));
  }
  if (j + 8 <= s1) {
    int e0 = csr[j + sub], e1 = csr[j + 4 + sub];
    unsigned w0 = *(const unsigned*)(src + (size_t)e0 * 64 + c16 * 4);
    unsigned w1 = *(const unsigned*)(src + (size_t)e1 * 64 + c16 * 4);
    a4[0] += FP8D(w0, 0) + FP8D(w1, 0);
    a4[1] += FP8D(w0, 1) + FP8D(w1, 1);
    a4[2] += FP8D(w0, 2) + FP8D(w1, 2);
    a4[3] += FP8D(w0, 3) + FP8D(w1, 3);
    j += 8;
  }
  if (j + 4 <= s1) {
    int e0 = csr[j + sub];
    unsigned w0 = *(const unsigned*)(src + (size_t)e0 * 64 + c16 * 4);
    a4[0] += FP8D(w0, 0); a4[1] += FP8D(w0, 1);
    a4[2] += FP8D(w0, 2); a4[3] += FP8D(w0, 3);
    j += 4;
  }
  int rem = s1 - j;
  if (sub < rem) {
    int e0 = csr[j + sub];
    unsigned w0 = *(const unsigned*)(src + (size_t)e0 * 64 + c16 * 4);
    a4[0] += FP8D(w0, 0); a4[1] += FP8D(w0, 1);
    a4[2] += FP8D(w0, 2); a4[3] += FP8D(w0, 3);
  }
  #pragma unroll
  for (int c = 0; c < 4; c++) {
    a4[c] += __shfl_xor(a4[c], 16, 64);
    a4[c] += __shfl_xor(a4[c], 32, 64);
  }
  float acc = sub == 0 ? a4[0] : sub == 1 ? a4[1] : sub == 2 ? a4[2] : a4[3];
  int col = c16 * 4 + sub;               // lane→column permutation
  float val = acc * ISCALE_E_ * frcp(fmaxf((float)(s1 - s0), 1.0f));
  size_t idx = (size_t)r * 64 + col;
  out[idx] = __float2bfloat16(val);
  unsigned p = fp8_enc_pk(val * SCALE_1_, val * SCALE_1_);
  out8[idx] = (unsigned char)(p & 0xFF);
}

// ---------------- 3. fused layer-2 aggregation + attention (fp8 dword gather) ---------
__global__ __launch_bounds__(256) void agg2attn_kernel(
    const unsigned char* __restrict__ u18, const unsigned char* __restrict__ i18,
    const __hip_bfloat16* __restrict__ u1, const __hip_bfloat16* __restrict__ i1,
    const void* __restrict__ ue, const void* __restrict__ ie,
    const int* __restrict__ rowU, const int* __restrict__ rowI,
    const int* __restrict__ csrU, const int* __restrict__ csrI,
    const float* __restrict__ vecs, float* __restrict__ hu, float* __restrict__ hi,
    const float* __restrict__ flag) {
  int isf32 = *flag > 0.5f;
  int wv = threadIdx.x >> 6, lane = threadIdx.x & 63;
  int sub = lane >> 4, c16 = lane & 15;
  int side = blockIdx.x >= I_ / 4;          // 0: item rows, 1: user rows
  int blk = side ? blockIdx.x - I_ / 4 : blockIdx.x;
  int r = blk * 4 + wv;
  const int* row = side ? rowU : rowI;
  const int* csr = side ? csrU : csrI;
  const unsigned char* opp8 = side ? i18 : u18;
  const __hip_bfloat16* own1 = side ? u1 : i1;
  const void* base = side ? ue : ie;
  float* h = side ? hu : hi;
  int s0 = row[r], s1 = row[r + 1];
  float a4[4] = {0.f, 0.f, 0.f, 0.f};
  int j = s0;
  for (; j + 16 <= s1; j += 16) {        // 4 gathers in flight
    int e0 = csr[j + sub], e1 = csr[j + 4 + sub];
    int e2 = csr[j + 8 + sub], e3 = csr[j + 12 + sub];
    unsigned w0 = *(const unsigned*)(opp8 + (size_t)e0 * 64 + c16 * 4);
    unsigned w1 = *(const unsigned*)(opp8 + (size_t)e1 * 64 + c16 * 4);
    unsigned w2 = *(const unsigned*)(opp8 + (size_t)e2 * 64 + c16 * 4);
    unsigned w3 = *(const unsigned*)(opp8 + (size_t)e3 * 64 + c16 * 4);
    a4[0] += (FP8D(w0, 0) + FP8D(w1, 0)) + (FP8D(w2, 0) + FP8D(w3, 0));
    a4[1] += (FP8D(w0, 1) + FP8D(w1, 1)) + (FP8D(w2, 1) + FP8D(w3, 1));
    a4[2] += (FP8D(w0, 2) + FP8D(w1, 2)) + (FP8D(w2, 2) + FP8D(w3, 2));
    a4[3] += (FP8D(w0, 3) + FP8D(w1, 3)) + (FP8D(w2, 3) + FP8D(w3, 3));
  }
  if (j + 8 <= s1) {
    int e0 = csr[j + sub], e1 = csr[j + 4 + sub];
    unsigned w0 = *(const unsigned*)(opp8 + (size_t)e0 * 64 + c16 * 4);
    unsigned w1 = *(const unsigned*)(opp8 + (size_t)e1 * 64 + c16 * 4);
    a4[0] += FP8D(w0, 0) + FP8D(w1, 0);
    a4[1] += FP8D(w0, 1) + FP8D(w1, 1);
    a4[2] += FP8D(w0, 2) + FP8D(w1, 2);
    a4[3] += FP8D(w0, 3) + FP8D(w1, 3);
    j += 8;
  }
  if (j + 4 <= s1) {
    int e0 = csr[j + sub];
    unsigned w0 = *(const unsigned*)(opp8 + (size_t)e0 * 64 + c16 * 4);
    a4[0] += FP8D(w0, 0); a4[1] += FP8D(w0, 1);
    a4[2] += FP8D(w0, 2); a4[3] += FP8D(w0, 3);
    j += 4;
  }
  int rem = s1 - j;
  if (sub < rem) {
    int e0 = csr[j + sub];
    unsigned w0 = *(const unsigned*)(opp8 + (size_t)e0 * 64 + c16 * 4);
    a4[0] += FP8D(w0, 0); a4[1] += FP8D(w0, 1);
    a4[2] += FP8D(w0, 2); a4[3] += FP8D(w0, 3);
  }
  #pragma unroll
  for (int c = 0; c < 4; c++) {
    a4[c] += __shfl_xor(a4[c], 16, 64);
    a4[c] += __shfl_xor(a4[c], 32, 64);
  }
  float acc = sub == 0 ? a4[0] : sub == 1 ? a4[1] : sub == 2 ? a4[2] : a4[3];
  int col = c16 * 4 + sub;               // lane→column permutation
  size_t idx = (size_t)r * 64 + col;
  float t2 = acc * ISCALE_1_ * frcp(fmaxf((float)(s1 - s0), 1.0f));
  float t0 = ldf(base, idx, isf32);
  float t1 = b2f(own1[idx]);
  float w = vecs[col];   // Wa
  float p0 = t0 * w, p1 = t1 * w, p2 = t2 * w;
  #pragma unroll
  for (int off = 32; off; off >>= 1) {
    p0 += __shfl_xor(p0, off, 64);
    p1 += __shfl_xor(p1, off, 64);
    p2 += __shfl_xor(p2, off, 64);
  }
  float m = fmaxf(p0, fmaxf(p1, p2));
  float e0 = __expf(p0 - m), e1 = __expf(p1 - m), e2 = __expf(p2 - m);
  float inv = 1.0f / (e0 + e1 + e2);
  h[idx] = (t0 * e0 + t1 * e1 + t2 * e2) * inv;
}

// ---------------- 5. contrastive loss: slim epilogue MFMA Gram ----------
constexpr int XS_ = 72;                   // f16 row stride (144 B)
constexpr float SC_  = 2.6857914f;        // sqrt(5*log2(e))
constexpr float EPS_ = 1e-6f;
constexpr float LN2_ = 0.6931471805599453f;
__global__ __launch_bounds__(1024) void contrast_kernel(
    const float* __restrict__ hu, const float* __restrict__ an,
    float* __restrict__ loss_acc) {
  __shared__ __align__(16) _Float16 Xh[512 * XS_];  // 72 KB
  __shared__ float iN[512];
  int tid = threadIdx.x;
  int c = blockIdx.x;

  // phase 1: all 1024 threads, 2 threads per row (half-row each)
  {
    int rid = tid >> 1, half = tid & 1;   // rid 0..511
    int row = rid & 255;
    const float* r1 = (rid < 256 ? hu : an) + ((size_t)c * CB_ + row) * 64 + half * 32;
    float4 a4[8];
    float s1 = 0.f;
    #pragma unroll
    for (int t = 0; t < 8; t++) {
      a4[t] = ((const float4*)r1)[t];
      s1 += a4[t].x * a4[t].x + a4[t].y * a4[t].y + a4[t].z * a4[t].z + a4[t].w * a4[t].w;
    }
    s1 += __shfl_xor(s1, 1, 64);          // combine the two halves
    float inv = frcp(sqrtf(s1));
    if (half == 0) iN[rid] = inv;
    float sc = inv * SC_;
    #pragma unroll
    for (int t = 0; t < 4; t++) {
      f16x8 v;
      v[0] = (_Float16)(a4[2*t].x * sc);   v[1] = (_Float16)(a4[2*t].y * sc);
      v[2] = (_Float16)(a4[2*t].z * sc);   v[3] = (_Float16)(a4[2*t].w * sc);
      v[4] = (_Float16)(a4[2*t+1].x * sc); v[5] = (_Float16)(a4[2*t+1].y * sc);
      v[6] = (_Float16)(a4[2*t+1].z * sc); v[7] = (_Float16)(a4[2*t+1].w * sc);
      *(f16x8*)&Xh[rid * XS_ + half * 32 + t * 8] = v;
    }
  }
  __syncthreads();

  int l = tid & 63, wv = tid >> 6;       // wv 0..15
  int n = l & 15, q = l >> 4;
  int rb = wv * 32;
  f16x8 A[2][2];
  #pragma unroll
  for (int t = 0; t < 2; t++) {
    A[t][0] = *(const f16x8*)&Xh[(rb + t * 16 + n) * XS_ + q * 8];
    A[t][1] = *(const f16x8*)&Xh[(rb + t * 16 + n) * XS_ + 32 + q * 8];
  }
  float eNiR[2][4];
  #pragma unroll
  for (int t = 0; t < 2; t++)
    #pragma unroll
    for (int r = 0; r < 4; r++)
      eNiR[t][r] = EPS_ * iN[rb + t * 16 + q * 4 + r];
  float sums[2][4] = {{0,0,0,0},{0,0,0,0}};
  float labs2[2] = {0, 0};
  int selfn = q * 4;
  const floatx4 zero = {0.f, 0.f, 0.f, 0.f};
  for (int ct = 0; ct < 32; ct++) {
    f16x8 B0 = *(const f16x8*)&Xh[(ct * 16 + n) * XS_ + q * 8];
    f16x8 B1 = *(const f16x8*)&Xh[(ct * 16 + n) * XS_ + 32 + q * 8];
    float iNj = iN[ct * 16 + n];
    #pragma unroll
    for (int t = 0; t < 2; t++) {
      floatx4 acc = __builtin_amdgcn_mfma_f32_16x16x32_f16(A[t][0], B0, zero, 0, 0, 0);
      acc = __builtin_amdgcn_mfma_f32_16x16x32_f16(A[t][1], B1, acc, 0, 0, 0);
      int rtg = wv * 2 + t;
      if (ct == (rtg ^ 16)) {
        #pragma unroll
        for (int r = 0; r < 4; r++) {
          float G = acc[r];
          float u = eNiR[t][r] * iNj;
          float s2 = __builtin_fmaf(G, -u, G);
          sums[t][r] += fexp2(s2);
          if (n == selfn + r) labs2[t] += s2;
        }
      } else if (ct == rtg) {
        #pragma unroll
        for (int r = 0; r < 4; r++) {
          float G = acc[r];
          float u = eNiR[t][r] * iNj;
          float s2 = __builtin_fmaf(G, -u, G);
          float e = (n == selfn + r) ? 0.f : fexp2(s2);
          sums[t][r] += e;
        }
      } else {
        #pragma unroll
        for (int r = 0; r < 4; r++) {
          float G = acc[r];
          float u = eNiR[t][r] * iNj;
          float s2 = __builtin_fmaf(G, -u, G);
          sums[t][r] += fexp2(s2);
        }
      }
    }
  }
  #pragma unroll
  for (int off = 1; off <= 8; off <<= 1) {
    #pragma unroll
    for (int t = 0; t < 2; t++) {
      #pragma unroll
      for (int r = 0; r < 4; r++) sums[t][r] += __shfl_xor(sums[t][r], off, 64);
      labs2[t] += __shfl_xor(labs2[t], off, 64);
    }
  }
  float part = 0.f;
  if (n == 0) {
    #pragma unroll
    for (int t = 0; t < 2; t++) {
      float lt = 0.f;
      #pragma unroll
      for (int r = 0; r < 4; r++) lt += __logf(sums[t][r]);
      part += lt - labs2[t] * LN2_;
    }
  }
  #pragma unroll
  for (int off = 1; off < 64; off <<= 1) part += __shfl_xor(part, off, 64);
  if (l == 0) atomicAdd(loss_acc, part);
}

// ---------------- 6. scores (+ fused finalize): 4 edges per wave ----------
__global__ __launch_bounds__(256) void score_kernel(
    const float* __restrict__ hu, const float* __restrict__ hi,
    const int* __restrict__ pu, const int* __restrict__ pi,
    const int* __restrict__ nu, const int* __restrict__ ni,
    void* __restrict__ out, const float* __restrict__ flag,
    const float* __restrict__ loss_acc) {
  int isf32 = *flag > 0.5f;
  // finalize fused here: contrast kernel has retired (same stream), loss_acc is final
  if (blockIdx.x == 0 && threadIdx.x == 0) {
    float v = loss_acc[0] * (1.0f / (float)(2 * CB_ * NCHUNK_));
    if (isf32) ((float*)out)[2 * EP_] = v;
    else       ((__hip_bfloat16*)out)[2 * EP_] = __float2bfloat16(v);
  }
  int lane = threadIdx.x & 63;
  int g = lane >> 4, c = lane & 15;     // group 0..3, lane-in-group
  int gw = blockIdx.x * 4 + (threadIdx.x >> 6);
  int w = gw * 4 + g;                    // edge id, < 2*EP_
  int uu, ii;
  if (w < EP_) { uu = pu[w]; ii = pi[w]; }
  else         { uu = nu[w - EP_]; ii = ni[w - EP_]; }
  float4 a = *(const float4*)(hu + (size_t)uu * 64 + c * 4);
  float4 b = *(const float4*)(hi + (size_t)ii * 64 + c * 4);
  float p = a.x * b.x + a.y * b.y + a.z * b.z + a.w * b.w;
  #pragma unroll
  for (int off = 1; off < 16; off <<= 1) p += __shfl_xor(p, off, 64);
  if (c == 0) {
    if (isf32) ((float*)out)[w] = p;
    else       ((__hip_bfloat16*)out)[w] = __float2bfloat16(p);
  }
}

// ---------------- launch ----------------
extern "C" void kernel_launch(void* const* d_in, const int* in_sizes, int n_in,
                              void* d_out, int out_size, void* d_ws, size_t ws_size,
                              hipStream_t stream) {
  const void* ue  = d_in[0];
  const void* ie  = d_in[1];
  const void* W   = d_in[2];
  const void* a   = d_in[3];
  const void* WU  = d_in[4];
  const void* aU  = d_in[5];
  const void* cw  = d_in[6];
  const int* rs  = (const int*)d_in[7];
  const int* rd  = (const int*)d_in[8];
  const int* pu  = (const int*)d_in[9];
  const int* pi  = (const int*)d_in[10];
  const int* nu  = (const int*)d_in[11];
  const int* ni  = (const int*)d_in[12];
  const int* nbr = (const int*)d_in[13];

  float* wsf  = (float*)d_ws;
  int*   wsi  = (int*)d_ws;
  float* loss = wsf + OFF_LOSS;
  float* flag = wsf + OFF_FLAG;
  int* curU   = wsi + OFF_CURU;
  int* curI   = wsi + OFF_CURI;
  float* vecs = wsf + OFF_VEC;
  int* rowU   = wsi + OFF_ROWU;
  int* rowI   = wsi + OFF_ROWI;
  int* csrU   = wsi + OFF_CSRU;
  int* csrI   = wsi + OFF_CSRI;
  __hip_bfloat16* u1 = (__hip_bfloat16*)(wsf + OFF_U1);
  __hip_bfloat16* i1 = (__hip_bfloat16*)(wsf + OFF_I1);
  float* hu   = wsf + OFF_HU;
  float* hi   = wsf + OFF_HI;
  float* anc  = wsf + OFF_ANC;
  unsigned char* ue8 = (unsigned char*)(wsf + OFF_UE8);
  unsigned char* ie8 = (unsigned char*)(wsf + OFF_IE8);
  unsigned char* u18 = (unsigned char*)(wsf + OFF_U18);
  unsigned char* i18 = (unsigned char*)(wsf + OFF_I18);
  unsigned* bufU = (unsigned*)(wsf + OFF_HU);
  unsigned* bufI = (unsigned*)(wsf + OFF_HI);

  // prep also zeroes loss + bucket counters (memset launch removed)
  prep_kernel<<<1, 256, 0, stream>>>((const unsigned short*)ue, W, a, WU, aU,
                                     vecs, flag, wsf);

  // fused: anchor + CSR Phase A + fp8 convert (all independent), LPT block order
  fusedA_kernel<<<NANC_ + NBA_ + NCVT_, 256, 0, stream>>>(
      rs, rd, bufU, bufI, curU, curI, ue, ie, WU, cw, vecs, nbr, anc, ue8, ie8, flag);

  // Phase B with per-block local scan
  bucketB_kernel<<<2 * NBK_, 256, 0, stream>>>(bufU, bufI, curU, curI,
                                               rowU, rowI, csrU, csrI);

  // fused layer-1 aggregation (fp8 dword gather, both sides)
  agg1_kernel<<<(I_ + U_) / 4, 256, 0, stream>>>(ue8, ie8, rowU, rowI, csrU, csrI,
                                                 u1, i1, u18, i18);
  // fused layer-2 aggregation + attention (fp8 dword gather, both sides)
  agg2attn_kernel<<<(I_ + U_) / 4, 256, 0, stream>>>(u18, i18, u1, i1, ue, ie,
                                                     rowU, rowI, csrU, csrI,
                                                     vecs, hu, hi, flag);

  // contrastive loss (dedicated CUs, 1024 threads)
  contrast_kernel<<<NCHUNK_, 1024, 0, stream>>>(hu, anc, loss);

  // scores + fused finalize (256-thr blocks, 4 edges/wave, high residency)
  score_kernel<<<NSCB_, 256, 0, stream>>>(hu, hi, pu, pi, nu, ni, d_out, flag, loss);
}

// Round 7
// 328.924 us; speedup vs baseline: 1.0363x; 1.0338x over previous
//
#include <hip/hip_runtime.h>
#include <hip/hip_bf16.h>

// ---------------- problem constants ----------------
constexpr int U_  = 51200;
constexpr int I_  = 25600;
constexpr int E_  = 1000000;
constexpr int EP_ = 100000;
constexpr int CB_ = 256;                 // contrastive chunk size
constexpr int NCHUNK_ = U_ / CB_;        // 200
constexpr size_t UD_ = (size_t)U_ * 64;
constexpr size_t ID_ = (size_t)I_ * 64;
constexpr int NBK_ = 200;                // buckets per side
constexpr int CAP_ = 8192;               // record slots per bucket
constexpr int TILE_ = 4096;              // edges per Phase-A block (proven best: round 4)
constexpr int NBA_ = (E_ + TILE_ - 1) / TILE_;  // 245
constexpr int NANC_ = U_ / 16;           // 3200 anchor blocks
constexpr int NCVT_ = (int)((UD_ + ID_) / (8 * 256));  // 2400 convert blocks (8 elem/thread)
constexpr int NSCB_ = (2 * EP_) / 16;    // 12500 score blocks (16 edges/block)

// fp8 scaling (values sit in e4m3 sweet range)
constexpr float SCALE_E_  = 16.f;   // raw embeddings ~0.1
constexpr float ISCALE_E_ = 1.f / 16.f;
constexpr float SCALE_1_  = 64.f;   // layer-1 aggregates ~0.02
constexpr float ISCALE_1_ = 1.f / 64.f;

// ---------------- workspace layout (4-byte element offsets) ----------------
constexpr size_t OFF_LOSS  = 0;
constexpr size_t OFF_FLAG  = 1;
constexpr size_t OFF_CURU  = 8;                      // 200 ints
constexpr size_t OFF_CURI  = 208;                    // 200 ints
constexpr size_t OFF_VEC   = 448;                    // 192 floats
constexpr size_t OFF_ROWU  = 1088;                   // U_+1
constexpr size_t OFF_ROWI  = ((OFF_ROWU + U_ + 1 + 63) / 64) * 64;   // I_+1
constexpr size_t OFF_CSRU  = ((OFF_ROWI + I_ + 1 + 63) / 64) * 64;   // E_
constexpr size_t OFF_CSRI  = OFF_CSRU + E_;          // E_
constexpr size_t OFF_U1    = ((OFF_CSRI + E_ + 63) / 64) * 64;       // UD_ (bf16)
constexpr size_t OFF_I1    = OFF_U1 + UD_;
constexpr size_t OFF_HU    = OFF_I1 + ID_;           // bufU aliases
constexpr size_t OFF_HI    = OFF_HU + UD_;           // bufI aliases
constexpr size_t OFF_ANC   = OFF_HI + ID_;
constexpr size_t OFF_UE8   = OFF_ANC + UD_;          // UD_ bytes (fp8)
constexpr size_t OFF_IE8   = OFF_UE8 + UD_ / 4;
constexpr size_t OFF_U18   = OFF_IE8 + ID_ / 4;
constexpr size_t OFF_I18   = OFF_U18 + UD_ / 4;
// total ≈ 65.6 MB

#define DEVI static __device__ __forceinline__

typedef _Float16 h2v __attribute__((ext_vector_type(2)));
typedef _Float16 f16x8 __attribute__((ext_vector_type(8)));
typedef float floatx4 __attribute__((ext_vector_type(4)));
typedef unsigned short u16x8 __attribute__((ext_vector_type(8)));

DEVI float b2f(__hip_bfloat16 x) { return __bfloat162float(x); }

DEVI float bfb2f(unsigned short b) {
  unsigned u = ((unsigned)b) << 16; float f; __builtin_memcpy(&f, &u, 4); return f;
}

DEVI float ldf(const void* p, size_t i, int isf32) {
  if (isf32) return ((const float*)p)[i];
  return b2f(((const __hip_bfloat16*)p)[i]);
}

DEVI float frcp(float x) { return __builtin_amdgcn_rcpf(x); }

DEVI float fexp2(float x) {
#if __has_builtin(__builtin_amdgcn_exp2f)
  return __builtin_amdgcn_exp2f(x);
#else
  return exp2f(x);
#endif
}

// fp8 e4m3 (OCP) decode/encode
DEVI float fp8_dec(unsigned v) {
#if __has_builtin(__builtin_amdgcn_cvt_f32_fp8)
  return __builtin_amdgcn_cvt_f32_fp8(v, 0);
#else
  unsigned b = v & 0xFF;
  if (!(b & 0x78)) return 0.f;  // flush subnormals (negligible at our scales)
  unsigned short h = (unsigned short)(((b & 0x80) << 8) | (((b & 0x7f) + (8 << 3)) << 7));
  _Float16 hf; __builtin_memcpy(&hf, &h, 2);
  return (float)hf;
#endif
}

// decode byte `s` (compile-time literal) of dword w
#if __has_builtin(__builtin_amdgcn_cvt_f32_fp8)
#define FP8D(w, s) __builtin_amdgcn_cvt_f32_fp8((w), (s))
#else
#define FP8D(w, s) fp8_dec(((w) >> (8 * (s))) & 0xFF)
#endif

DEVI unsigned fp8_enc_pk(float a, float b) {
#if __has_builtin(__builtin_amdgcn_cvt_pk_fp8_f32)
  return __builtin_amdgcn_cvt_pk_fp8_f32(a, b, 0u, false);
#else
  auto enc1 = [](float f) -> unsigned {
    _Float16 hf = (_Float16)f; unsigned short hb; __builtin_memcpy(&hb, &hf, 2);
    int s = hb >> 15, e = (hb >> 10) & 31, m = hb & 1023;
    int e8 = e - 15 + 7;
    int m3 = (m + ((1 << 6) + ((m >> 7) & 1))) >> 7;
    if (m3 > 7) { m3 = 0; e8++; }
    if (e8 <= 0) return (unsigned)(s << 7);
    if (e8 > 15) { e8 = 15; m3 = 6; }
    return (unsigned)((s << 7) | (e8 << 3) | m3);
  };
  return enc1(a) | (enc1(b) << 8);
#endif
}

DEVI int waveInclScan(int v, int lane) {
  #pragma unroll
  for (int off = 1; off < 64; off <<= 1) {
    int t = __shfl_up(v, off, 64);
    if (lane >= off) v += t;
  }
  return v;
}

// ---------------- 0. prep (also zeroes loss + bucket counters) ----------------
__global__ void prep_kernel(const unsigned short* __restrict__ ueu,
                            const void* __restrict__ W, const void* __restrict__ a,
                            const void* __restrict__ WU, const void* __restrict__ aU,
                            float* __restrict__ vecs, float* __restrict__ flag,
                            float* __restrict__ ws0) {
  int tid = threadIdx.x;
  for (int i = tid; i < 408; i += 256)
    if (i == 0 || i >= 8) ws0[i] = 0.f;
  if (tid < 64) {
    int cnt = 0;
    for (int i = 0; i < 256; i++) {
      int e = (ueu[i] >> 7) & 0xFF;
      if (e >= 130) cnt++;
    }
    int isf32 = (cnt >= 8);
    if (tid == 0) *flag = isf32 ? 1.0f : 0.0f;
    int d = tid;
    float s = 0.f, t1 = 0.f, t2 = 0.f;
    for (int e = 0; e < 64; e++) {
      s += ldf(W, d * 64 + e, isf32) * ldf(a, e, isf32);
      float wue = ldf(WU, d * 64 + e, isf32);
      t1 += wue * ldf(aU, e, isf32);
      t2 += wue * ldf(aU, 64 + e, isf32);
    }
    vecs[d] = s;
    vecs[64 + d] = t1;
    vecs[128 + d] = t2;
  }
}

// ---------------- fused A: bucketA + anchor + fp8-convert (round-4 proven order) ------
struct BktSmem {            // ~39.4 KB at TILE_=4096
  int histU[NBK_], histI[NBK_];
  int loffU[NBK_ + 1], loffI[NBK_ + 1];
  int cbU[NBK_], cbI[NBK_];
  int lcU[NBK_], lcI[NBK_];
  int wsU[4], wsI[4];
  unsigned recsU[TILE_], recsI[TILE_];
};
constexpr int WS_ = 72;
struct AncSmem {            // ~11.6 KB
  _Float16 WUt[64 * WS_];
  _Float16 mixS[16 * WS_];
  float invSe[16];
  int nbrS[128];
};
constexpr size_t FSA_SMEM = sizeof(BktSmem) > sizeof(AncSmem) ? sizeof(BktSmem) : sizeof(AncSmem);

DEVI void bucketA_body(char* smemRaw, int blk,
    const int* __restrict__ rs, const int* __restrict__ rd,
    unsigned* __restrict__ bufU, unsigned* __restrict__ bufI,
    int* __restrict__ curU, int* __restrict__ curI) {
  BktSmem& S = *(BktSmem*)smemRaw;
  int tid = threadIdx.x;
  int base = blk * TILE_;
  for (int i = tid; i < NBK_; i += 256) { S.histU[i] = 0; S.histI[i] = 0; }
  __syncthreads();
  int ss[16], dd[16];
  #pragma unroll
  for (int t = 0; t < 16; t++) {
    int e = base + t * 256 + tid;
    bool v = e < E_;
    ss[t] = v ? rs[e] : -1;
    dd[t] = v ? rd[e] : 0;
    if (v) {
      atomicAdd(&S.histU[ss[t] >> 8], 1);
      atomicAdd(&S.histI[dd[t] >> 7], 1);
    }
  }
  __syncthreads();
  if (tid < NBK_) {
    int cU = S.histU[tid];
    S.cbU[tid] = tid * CAP_ + (cU ? atomicAdd(&curU[tid], cU) : 0);
    int cI = S.histI[tid];
    S.cbI[tid] = tid * CAP_ + (cI ? atomicAdd(&curI[tid], cI) : 0);
  }
  int lane = tid & 63, wv = tid >> 6;
  int cvU = (tid < NBK_) ? S.histU[tid] : 0;
  int cvI = (tid < NBK_) ? S.histI[tid] : 0;
  int inU = waveInclScan(cvU, lane);
  int inI = waveInclScan(cvI, lane);
  if (lane == 63) { S.wsU[wv] = inU; S.wsI[wv] = inI; }
  __syncthreads();
  int woU = 0, woI = 0;
  for (int w = 0; w < wv; w++) { woU += S.wsU[w]; woI += S.wsI[w]; }
  if (tid < NBK_) {
    S.loffU[tid] = woU + inU - cvU;
    S.loffI[tid] = woI + inI - cvI;
  }
  if (tid == NBK_ - 1) {
    S.loffU[NBK_] = woU + inU;
    S.loffI[NBK_] = woI + inI;
  }
  __syncthreads();
  if (tid < NBK_) { S.lcU[tid] = S.loffU[tid]; S.lcI[tid] = S.loffI[tid]; }
  __syncthreads();
  #pragma unroll
  for (int t = 0; t < 16; t++) {
    if (ss[t] >= 0) {
      int b = ss[t] >> 8;
      int p = atomicAdd(&S.lcU[b], 1);
      S.recsU[p] = ((unsigned)(ss[t] & 255) << 17) | (unsigned)dd[t];
      b = dd[t] >> 7;
      p = atomicAdd(&S.lcI[b], 1);
      S.recsI[p] = ((unsigned)(dd[t] & 127) << 17) | (unsigned)ss[t];
    }
  }
  __syncthreads();
  int totU = S.loffU[NBK_];
  for (int p = tid; p < totU; p += 256) {
    int lo = 0, hi = NBK_;
    while (hi - lo > 1) { int mid = (lo + hi) >> 1; if (S.loffU[mid] <= p) lo = mid; else hi = mid; }
    bufU[S.cbU[lo] + (p - S.loffU[lo])] = S.recsU[p];
  }
  int totI = S.loffI[NBK_];
  for (int p = tid; p < totI; p += 256) {
    int lo = 0, hi = NBK_;
    while (hi - lo > 1) { int mid = (lo + hi) >> 1; if (S.loffI[mid] <= p) lo = mid; else hi = mid; }
    bufI[S.cbI[lo] + (p - S.loffI[lo])] = S.recsI[p];
  }
}

// anchor: FFT-filter + neighbor attention (distributed multi-value reductions)
DEVI void anchor_body(char* smemRaw, int blk,
    const void* __restrict__ ue, const void* __restrict__ WU,
    const void* __restrict__ cw, const float* __restrict__ vecs,
    const int* __restrict__ nbr, float* __restrict__ out, int isf32) {
  AncSmem& S = *(AncSmem*)smemRaw;
  int tid = threadIdx.x;
  int wv = tid >> 6, lane = tid & 63;
  int ublk = blk * 16;

  #pragma unroll
  for (int it = 0; it < 16; it++) {
    int k = it * 4 + wv;
    S.WUt[lane * WS_ + k] = (_Float16)ldf(WU, (size_t)k * 64 + lane, isf32);
  }
  if (tid < 128) S.nbrS[tid] = nbr[ublk * 8 + tid];
  __syncthreads();

  float cw0 = ldf(cw, (0 * 64 + lane) * 2, isf32);
  float w1r = ldf(cw, (1 * 64 + lane) * 2, isf32), w1i = ldf(cw, (1 * 64 + lane) * 2 + 1, isf32);
  float w2r = ldf(cw, (2 * 64 + lane) * 2, isf32), w2i = ldf(cw, (2 * 64 + lane) * 2 + 1, isf32);
  float w3r = ldf(cw, (3 * 64 + lane) * 2, isf32), w3i = ldf(cw, (3 * 64 + lane) * 2 + 1, isf32);
  float cw4 = ldf(cw, (4 * 64 + lane) * 2, isf32);
  float v1 = vecs[64 + lane], v2 = vecs[128 + lane];
  const float c1 = 0.70710678118654752440f;

  bool b3 = (lane & 8) != 0, b4 = (lane & 16) != 0, b5 = (lane & 32) != 0;

  // q for the wave's 4 users: distributed reduce over lane-bit-{4,5}
  float qv0 = ldf(ue, (size_t)(ublk + wv * 4 + 0) * 64 + lane, isf32) * v2;
  float qv1 = ldf(ue, (size_t)(ublk + wv * 4 + 1) * 64 + lane, isf32) * v2;
  float qv2 = ldf(ue, (size_t)(ublk + wv * 4 + 2) * 64 + lane, isf32) * v2;
  float qv3 = ldf(ue, (size_t)(ublk + wv * 4 + 3) * 64 + lane, isf32) * v2;
  qv0 += __shfl_xor(qv0, 16, 64); qv0 += __shfl_xor(qv0, 32, 64);
  qv1 += __shfl_xor(qv1, 16, 64); qv1 += __shfl_xor(qv1, 32, 64);
  qv2 += __shfl_xor(qv2, 16, 64); qv2 += __shfl_xor(qv2, 32, 64);
  qv3 += __shfl_xor(qv3, 16, 64); qv3 += __shfl_xor(qv3, 32, 64);
  float qs0 = b4 ? qv1 : qv0;
  float qs1 = b4 ? qv3 : qv2;
  float qw = b5 ? qs1 : qs0;
  qw += __shfl_xor(qw, 1, 64); qw += __shfl_xor(qw, 2, 64);
  qw += __shfl_xor(qw, 4, 64); qw += __shfl_xor(qw, 8, 64);
  // lane l now holds Q[l>>4]

  float xc[8], xn[8];
  #pragma unroll
  for (int k = 0; k < 8; k++)
    xc[k] = ldf(ue, (size_t)S.nbrS[wv * 32 + k] * 64 + lane, isf32);

  for (int u4 = 0; u4 < 4; u4++) {
    int uL = wv * 4 + u4;
    if (u4 < 3) {
      #pragma unroll
      for (int k = 0; k < 8; k++)
        xn[k] = ldf(ue, (size_t)S.nbrS[wv * 32 + (u4 + 1) * 8 + k] * 64 + lane, isf32);
    }
    float sA = xc[1] - xc[3] - xc[5] + xc[7];
    float sB = xc[1] + xc[3] - xc[5] - xc[7];
    float ev = (xc[0] + xc[4]) + (xc[2] + xc[6]);
    float od = (xc[1] + xc[5]) + (xc[3] + xc[7]);
    float d04 = xc[0] - xc[4], d26 = xc[2] - xc[6];
    float X0r = ev + od;
    float X1r = d04 + c1 * sA;
    float X1i = -d26 - c1 * sB;
    float X2r = (xc[0] + xc[4]) - (xc[2] + xc[6]);
    float X2i = -(xc[1] - xc[3] + xc[5] - xc[7]);
    float X3r = d04 - c1 * sA;
    float X3i = d26 - c1 * sB;
    float X4r = ev - od;
    float Zr0 = X0r * cw0;
    float Zr1 = X1r * w1r - X1i * w1i, Zi1 = X1r * w1i + X1i * w1r;
    float Zr2 = X2r * w2r - X2i * w2i, Zi2 = X2r * w2i + X2i * w2r;
    float Zr3 = X3r * w3r - X3i * w3i, Zi3 = X3r * w3i + X3i * w3r;
    float Zr4 = X4r * cw4;
    float eP = Zr0 + Zr4, eM = Zr0 - Zr4;
    float t1 = c1 * (Zr1 - Zr3), t2 = c1 * (Zi1 + Zi3);
    float y[8];
    y[0] = eP + 2.f * (Zr1 + Zr2 + Zr3);
    y[1] = eM + 2.f * (t1 - t2 - Zi2);
    y[2] = eP + 2.f * (-Zi1 - Zr2 + Zi3);
    y[3] = eM + 2.f * (-t1 - t2 + Zi2);
    y[4] = eP + 2.f * (-Zr1 + Zr2 - Zr3);
    y[5] = eM + 2.f * (-t1 + t2 - Zi2);
    y[6] = eP + 2.f * (Zi1 - Zr2 - Zi3);
    y[7] = eM + 2.f * (t1 + t2 + Zi2);
    #pragma unroll
    for (int k = 0; k < 8; k++) y[k] *= 0.125f;

    // 8 dot-products vs v1: distributed reduce
    float p0 = y[0] * v1, p1 = y[1] * v1, p2 = y[2] * v1, p3 = y[3] * v1;
    float p4 = y[4] * v1, p5 = y[5] * v1, p6 = y[6] * v1, p7 = y[7] * v1;
    p0 += __shfl_xor(p0, 8, 64);  p0 += __shfl_xor(p0, 16, 64); p0 += __shfl_xor(p0, 32, 64);
    p1 += __shfl_xor(p1, 8, 64);  p1 += __shfl_xor(p1, 16, 64); p1 += __shfl_xor(p1, 32, 64);
    p2 += __shfl_xor(p2, 8, 64);  p2 += __shfl_xor(p2, 16, 64); p2 += __shfl_xor(p2, 32, 64);
    p3 += __shfl_xor(p3, 8, 64);  p3 += __shfl_xor(p3, 16, 64); p3 += __shfl_xor(p3, 32, 64);
    p4 += __shfl_xor(p4, 8, 64);  p4 += __shfl_xor(p4, 16, 64); p4 += __shfl_xor(p4, 32, 64);
    p5 += __shfl_xor(p5, 8, 64);  p5 += __shfl_xor(p5, 16, 64); p5 += __shfl_xor(p5, 32, 64);
    p6 += __shfl_xor(p6, 8, 64);  p6 += __shfl_xor(p6, 16, 64); p6 += __shfl_xor(p6, 32, 64);
    p7 += __shfl_xor(p7, 8, 64);  p7 += __shfl_xor(p7, 16, 64); p7 += __shfl_xor(p7, 32, 64);
    float a0 = b3 ? p1 : p0;
    float a1 = b3 ? p3 : p2;
    float a2 = b3 ? p5 : p4;
    float a3 = b3 ? p7 : p6;
    float c0 = b4 ? a1 : a0;
    float c1s = b4 ? a3 : a2;
    float w = b5 ? c1s : c0;
    w += __shfl_xor(w, 1, 64); w += __shfl_xor(w, 2, 64); w += __shfl_xor(w, 4, 64);
    // lane l holds EK[l>>3]

    float qu = __shfl(qw, u4 * 16, 64);
    float v = w + qu;
    v = v > 0.f ? v : 0.1f * v;              // LeakyReLU(0.1)
    float m = v;
    m = fmaxf(m, __shfl_xor(m, 8, 64));
    m = fmaxf(m, __shfl_xor(m, 16, 64));
    m = fmaxf(m, __shfl_xor(m, 32, 64));
    float wexp = __expf(v - m);
    float se = wexp;
    se += __shfl_xor(se, 8, 64); se += __shfl_xor(se, 16, 64); se += __shfl_xor(se, 32, 64);
    float mix = 0.f;
    #pragma unroll
    for (int k = 0; k < 8; k++)
      mix += __shfl(wexp, k * 8, 64) * y[k];
    S.mixS[uL * WS_ + lane] = (_Float16)mix;
    if (lane == 0) S.invSe[uL] = frcp(se);
    #pragma unroll
    for (int k = 0; k < 8; k++) xc[k] = xn[k];
  }
  __syncthreads();

  int n = lane & 15, qd = lane >> 4;
  f16x8 A0 = *(const f16x8*)&S.mixS[(lane & 15) * WS_ + qd * 8];
  f16x8 A1 = *(const f16x8*)&S.mixS[(lane & 15) * WS_ + 32 + qd * 8];
  f16x8 B0 = *(const f16x8*)&S.WUt[(wv * 16 + n) * WS_ + qd * 8];
  f16x8 B1 = *(const f16x8*)&S.WUt[(wv * 16 + n) * WS_ + 32 + qd * 8];
  const floatx4 zero = {0.f, 0.f, 0.f, 0.f};
  floatx4 acc = __builtin_amdgcn_mfma_f32_16x16x32_f16(A0, B0, zero, 0, 0, 0);
  acc = __builtin_amdgcn_mfma_f32_16x16x32_f16(A1, B1, acc, 0, 0, 0);
  #pragma unroll
  for (int r = 0; r < 4; r++) {
    int m = qd * 4 + r;
    out[(size_t)(ublk + m) * 64 + wv * 16 + n] = acc[r] * S.invSe[m];
  }
}

// 8 elements per thread, vector loads (fp32: 2×float4, bf16: 1×ushort8)
DEVI void convert_body(int blk, const void* __restrict__ ue, const void* __restrict__ ie,
                       unsigned char* __restrict__ ue8, unsigned char* __restrict__ ie8,
                       int isf32) {
  size_t t = (size_t)blk * 256 + threadIdx.x;   // 8-element group index
  const void* src; unsigned* dst; size_t o;
  if (t < UD_ / 8) { src = ue; dst = (unsigned*)ue8; o = t; }
  else             { src = ie; dst = (unsigned*)ie8; o = t - UD_ / 8; }
  float v[8];
  if (isf32) {
    float4 f0 = ((const float4*)src)[2 * o];
    float4 f1 = ((const float4*)src)[2 * o + 1];
    v[0] = f0.x; v[1] = f0.y; v[2] = f0.z; v[3] = f0.w;
    v[4] = f1.x; v[5] = f1.y; v[6] = f1.z; v[7] = f1.w;
  } else {
    u16x8 h = ((const u16x8*)src)[o];
    #pragma unroll
    for (int i = 0; i < 8; i++) v[i] = bfb2f(h[i]);
  }
  unsigned lo = fp8_enc_pk(v[0] * SCALE_E_, v[1] * SCALE_E_) |
                (fp8_enc_pk(v[2] * SCALE_E_, v[3] * SCALE_E_) << 16);
  unsigned hi = fp8_enc_pk(v[4] * SCALE_E_, v[5] * SCALE_E_) |
                (fp8_enc_pk(v[6] * SCALE_E_, v[7] * SCALE_E_) << 16);
  dst[2 * o]     = lo;
  dst[2 * o + 1] = hi;
}

__global__ __launch_bounds__(256) void fusedA_kernel(
    const int* __restrict__ rs, const int* __restrict__ rd,
    unsigned* __restrict__ bufU, unsigned* __restrict__ bufI,
    int* __restrict__ curU, int* __restrict__ curI,
    const void* __restrict__ ue, const void* __restrict__ ie,
    const void* __restrict__ WU, const void* __restrict__ cw,
    const float* __restrict__ vecs, const int* __restrict__ nbr,
    float* __restrict__ anc, unsigned char* __restrict__ ue8,
    unsigned char* __restrict__ ie8, const float* __restrict__ flag) {
  __shared__ __align__(16) char smem[FSA_SMEM];
  // round-4 proven order: bucketA -> anchor -> convert (heterogeneous CU mix)
  if (blockIdx.x < NBA_) {
    bucketA_body(smem, blockIdx.x, rs, rd, bufU, bufI, curU, curI);
  } else if (blockIdx.x < NBA_ + NANC_) {
    anchor_body(smem, blockIdx.x - NBA_, ue, WU, cw, vecs, nbr, anc, *flag > 0.5f);
  } else {
    convert_body(blockIdx.x - NBA_ - NANC_, ue, ie, ue8, ie8, *flag > 0.5f);
  }
}

// ---------------- 1c. Phase B (with per-block local bucket scan) ----------------
struct BktBSmem {
  int stage[CAP_];
  int cntk[256], offk[256];
  int exclS[256];
  int wsum[4], wsum2[4];
};

__global__ __launch_bounds__(256) void bucketB_kernel(
    const unsigned* __restrict__ bufU, const unsigned* __restrict__ bufI,
    const int* __restrict__ curU, const int* __restrict__ curI,
    int* __restrict__ rowU, int* __restrict__ rowI,
    int* __restrict__ csrU, int* __restrict__ csrI) {
  __shared__ __align__(16) BktBSmem S;
  int tid = threadIdx.x, b = blockIdx.x;
  int side = b >= NBK_;
  int bb = side ? b - NBK_ : b;
  const unsigned* src = (side ? bufI : bufU) + (size_t)bb * CAP_;
  const int* cur = side ? curI : curU;
  int total = cur[bb];
  int kpb   = side ? 128 : 256;
  int* rowptr = side ? rowI : rowU;
  int* csr    = side ? csrI : csrU;
  if (b == 0 && tid == 0) { rowU[U_] = E_; rowI[I_] = E_; }
  int lane = tid & 63, wv = tid >> 6;
  // local exclusive scan of cur[0..NBK_) -> gbase
  {
    int v = (tid < NBK_) ? cur[tid] : 0;
    int incl = waveInclScan(v, lane);
    if (lane == 63) S.wsum2[wv] = incl;
    S.cntk[tid] = 0;
    __syncthreads();
    int off = 0;
    for (int w = 0; w < wv; w++) off += S.wsum2[w];
    if (tid < NBK_) S.exclS[tid] = off + incl - v;
    __syncthreads();
  }
  int gbase = S.exclS[bb];
  for (int r = tid; r < total; r += 256) atomicAdd(&S.cntk[src[r] >> 17], 1);
  __syncthreads();
  int cv = (tid < kpb) ? S.cntk[tid] : 0;
  int incl = waveInclScan(cv, lane);
  if (lane == 63) S.wsum[wv] = incl;
  __syncthreads();
  int wvoff = 0;
  for (int w = 0; w < wv; w++) wvoff += S.wsum[w];
  int excl = wvoff + incl - cv;
  if (tid < kpb) {
    S.offk[tid] = excl;
    rowptr[bb * kpb + tid] = gbase + excl;
  }
  __syncthreads();
  for (int r = tid; r < total; r += 256) {
    unsigned rec = src[r];
    int slot = atomicAdd(&S.offk[rec >> 17], 1);
    if (slot < CAP_) S.stage[slot] = (int)(rec & 0x1FFFFu);
  }
  __syncthreads();
  for (int s = tid; s < total; s += 256) csr[gbase + s] = S.stage[s];
}

// ---------------- 2. fused layer-1 aggregation (fp8 dword gather, bf16+fp8 out) -------
// lane = sub*16 + c16; each lane loads one dword (4 fp8 cols) of edge csr[j+sub]
__global__ __launch_bounds__(256) void agg1_kernel(
    const unsigned char* __restrict__ ue8, const unsigned char* __restrict__ ie8,
    const int* __restrict__ rowU, const int* __restrict__ rowI,
    const int* __restrict__ csrU, const int* __restrict__ csrI,
    __hip_bfloat16* __restrict__ u1, __hip_bfloat16* __restrict__ i1,
    unsigned char* __restrict__ u18, unsigned char* __restrict__ i18) {
  int wv = threadIdx.x >> 6, lane = threadIdx.x & 63;
  int sub = lane >> 4, c16 = lane & 15;
  int side = blockIdx.x >= I_ / 4;          // 0: item rows (gather ue8), 1: user rows
  int blk = side ? blockIdx.x - I_ / 4 : blockIdx.x;
  int r = blk * 4 + wv;
  const int* row = side ? rowU : rowI;
  const int* csr = side ? csrU : csrI;
  const unsigned char* src = side ? ie8 : ue8;
  __hip_bfloat16* out = side ? u1 : i1;
  unsigned char* out8 = side ? u18 : i18;
  int s0 = row[r], s1 = row[r + 1];
  float a4[4] = {0.f, 0.f, 0.f, 0.f};
  int j = s0;
  for (; j + 16 <= s1; j += 16) {        // 4 gathers in flight
    int e0 = csr[j + sub], e1 = csr[j + 4 + sub];
    int e2 = csr[j + 8 + sub], e3 = csr[j + 12 + sub];
    unsigned w0 = *(const unsigned*)(src + (size_t)e0 * 64 + c16 * 4);
    unsigned w1 = *(const unsigned*)(src + (size_t)e1 * 64 + c16 * 4);
    unsigned w2 = *(const unsigned*)(src + (size_t)e2 * 64 + c16 * 4);
    unsigned w3 = *(const unsigned*)(src + (size_t)e3 * 64 + c16 * 4);
    a4[0] += (FP8D(w0, 0) + FP8D(w1, 0)) + (FP8D(w2, 0) + FP8D(w3, 0));
    a4[1] += (FP8D(w0, 1) + FP8D(w1, 1)) + (FP8D(w2, 1) + FP8D(w3, 1));
    a4[2] += (FP8D(w0, 2) + FP8D(w1, 2)) + (FP8D(w2, 2) + FP8D(w3, 2));
    a4[3] += (FP8D(w0, 3) + FP8D(w1, 3)) + (FP8D(w2, 3) + FP8D(w3, 3));
  }
  if (j + 8 <= s1) {
    int e0 = csr[j + sub], e1 = csr[j + 4 + sub];
    unsigned w0 = *(const unsigned*)(src + (size_t)e0 * 64 + c16 * 4);
    unsigned w1 = *(const unsigned*)(src + (size_t)e1 * 64 + c16 * 4);
    a4[0] += FP8D(w0, 0) + FP8D(w1, 0);
    a4[1] += FP8D(w0, 1) + FP8D(w1, 1);
    a4[2] += FP8D(w0, 2) + FP8D(w1, 2);
    a4[3] += FP8D(w0, 3) + FP8D(w1, 3);
    j += 8;
  }
  if (j + 4 <= s1) {
    int e0 = csr[j + sub];
    unsigned w0 = *(const unsigned*)(src + (size_t)e0 * 64 + c16 * 4);
    a4[0] += FP8D(w0, 0); a4[1] += FP8D(w0, 1);
    a4[2] += FP8D(w0, 2); a4[3] += FP8D(w0, 3);
    j += 4;
  }
  int rem = s1 - j;
  if (sub < rem) {
    int e0 = csr[j + sub];
    unsigned w0 = *(const unsigned*)(src + (size_t)e0 * 64 + c16 * 4);
    a4[0] += FP8D(w0, 0); a4[1] += FP8D(w0, 1);
    a4[2] += FP8D(w0, 2); a4[3] += FP8D(w0, 3);
  }
  #pragma unroll
  for (int c = 0; c < 4; c++) {
    a4[c] += __shfl_xor(a4[c], 16, 64);
    a4[c] += __shfl_xor(a4[c], 32, 64);
  }
  float acc = sub == 0 ? a4[0] : sub == 1 ? a4[1] : sub == 2 ? a4[2] : a4[3];
  int col = c16 * 4 + sub;               // lane→column permutation
  float val = acc * ISCALE_E_ * frcp(fmaxf((float)(s1 - s0), 1.0f));
  size_t idx = (size_t)r * 64 + col;
  out[idx] = __float2bfloat16(val);
  unsigned p = fp8_enc_pk(val * SCALE_1_, val * SCALE_1_);
  out8[idx] = (unsigned char)(p & 0xFF);
}

// ---------------- 3. fused layer-2 aggregation + attention (fp8 dword gather) ---------
__global__ __launch_bounds__(256) void agg2attn_kernel(
    const unsigned char* __restrict__ u18, const unsigned char* __restrict__ i18,
    const __hip_bfloat16* __restrict__ u1, const __hip_bfloat16* __restrict__ i1,
    const void* __restrict__ ue, const void* __restrict__ ie,
    const int* __restrict__ rowU, const int* __restrict__ rowI,
    const int* __restrict__ csrU, const int* __restrict__ csrI,
    const float* __restrict__ vecs, float* __restrict__ hu, float* __restrict__ hi,
    const float* __restrict__ flag) {
  int isf32 = *flag > 0.5f;
  int wv = threadIdx.x >> 6, lane = threadIdx.x & 63;
  int sub = lane >> 4, c16 = lane & 15;
  int side = blockIdx.x >= I_ / 4;          // 0: item rows, 1: user rows
  int blk = side ? blockIdx.x - I_ / 4 : blockIdx.x;
  int r = blk * 4 + wv;
  const int* row = side ? rowU : rowI;
  const int* csr = side ? csrU : csrI;
  const unsigned char* opp8 = side ? i18 : u18;
  const __hip_bfloat16* own1 = side ? u1 : i1;
  const void* base = side ? ue : ie;
  float* h = side ? hu : hi;
  int s0 = row[r], s1 = row[r + 1];
  float a4[4] = {0.f, 0.f, 0.f, 0.f};
  int j = s0;
  for (; j + 16 <= s1; j += 16) {        // 4 gathers in flight
    int e0 = csr[j + sub], e1 = csr[j + 4 + sub];
    int e2 = csr[j + 8 + sub], e3 = csr[j + 12 + sub];
    unsigned w0 = *(const unsigned*)(opp8 + (size_t)e0 * 64 + c16 * 4);
    unsigned w1 = *(const unsigned*)(opp8 + (size_t)e1 * 64 + c16 * 4);
    unsigned w2 = *(const unsigned*)(opp8 + (size_t)e2 * 64 + c16 * 4);
    unsigned w3 = *(const unsigned*)(opp8 + (size_t)e3 * 64 + c16 * 4);
    a4[0] += (FP8D(w0, 0) + FP8D(w1, 0)) + (FP8D(w2, 0) + FP8D(w3, 0));
    a4[1] += (FP8D(w0, 1) + FP8D(w1, 1)) + (FP8D(w2, 1) + FP8D(w3, 1));
    a4[2] += (FP8D(w0, 2) + FP8D(w1, 2)) + (FP8D(w2, 2) + FP8D(w3, 2));
    a4[3] += (FP8D(w0, 3) + FP8D(w1, 3)) + (FP8D(w2, 3) + FP8D(w3, 3));
  }
  if (j + 8 <= s1) {
    int e0 = csr[j + sub], e1 = csr[j + 4 + sub];
    unsigned w0 = *(const unsigned*)(opp8 + (size_t)e0 * 64 + c16 * 4);
    unsigned w1 = *(const unsigned*)(opp8 + (size_t)e1 * 64 + c16 * 4);
    a4[0] += FP8D(w0, 0) + FP8D(w1, 0);
    a4[1] += FP8D(w0, 1) + FP8D(w1, 1);
    a4[2] += FP8D(w0, 2) + FP8D(w1, 2);
    a4[3] += FP8D(w0, 3) + FP8D(w1, 3);
    j += 8;
  }
  if (j + 4 <= s1) {
    int e0 = csr[j + sub];
    unsigned w0 = *(const unsigned*)(opp8 + (size_t)e0 * 64 + c16 * 4);
    a4[0] += FP8D(w0, 0); a4[1] += FP8D(w0, 1);
    a4[2] += FP8D(w0, 2); a4[3] += FP8D(w0, 3);
    j += 4;
  }
  int rem = s1 - j;
  if (sub < rem) {
    int e0 = csr[j + sub];
    unsigned w0 = *(const unsigned*)(opp8 + (size_t)e0 * 64 + c16 * 4);
    a4[0] += FP8D(w0, 0); a4[1] += FP8D(w0, 1);
    a4[2] += FP8D(w0, 2); a4[3] += FP8D(w0, 3);
  }
  #pragma unroll
  for (int c = 0; c < 4; c++) {
    a4[c] += __shfl_xor(a4[c], 16, 64);
    a4[c] += __shfl_xor(a4[c], 32, 64);
  }
  float acc = sub == 0 ? a4[0] : sub == 1 ? a4[1] : sub == 2 ? a4[2] : a4[3];
  int col = c16 * 4 + sub;               // lane→column permutation
  size_t idx = (size_t)r * 64 + col;
  float t2 = acc * ISCALE_1_ * frcp(fmaxf((float)(s1 - s0), 1.0f));
  float t0 = ldf(base, idx, isf32);
  float t1 = b2f(own1[idx]);
  float w = vecs[col];   // Wa
  float p0 = t0 * w, p1 = t1 * w, p2 = t2 * w;
  #pragma unroll
  for (int off = 32; off; off >>= 1) {
    p0 += __shfl_xor(p0, off, 64);
    p1 += __shfl_xor(p1, off, 64);
    p2 += __shfl_xor(p2, off, 64);
  }
  float m = fmaxf(p0, fmaxf(p1, p2));
  float e0 = __expf(p0 - m), e1 = __expf(p1 - m), e2 = __expf(p2 - m);
  float inv = 1.0f / (e0 + e1 + e2);
  h[idx] = (t0 * e0 + t1 * e1 + t2 * e2) * inv;
}

// ---------------- 5. contrastive loss: slim epilogue MFMA Gram ----------
constexpr int XS_ = 72;                   // f16 row stride (144 B)
constexpr float SC_  = 2.6857914f;        // sqrt(5*log2(e))
constexpr float EPS_ = 1e-6f;
constexpr float LN2_ = 0.6931471805599453f;
__global__ __launch_bounds__(1024) void contrast_kernel(
    const float* __restrict__ hu, const float* __restrict__ an,
    float* __restrict__ loss_acc) {
  __shared__ __align__(16) _Float16 Xh[512 * XS_];  // 72 KB
  __shared__ float iN[512];
  int tid = threadIdx.x;
  int c = blockIdx.x;

  // phase 1: all 1024 threads, 2 threads per row (half-row each)
  {
    int rid = tid >> 1, half = tid & 1;   // rid 0..511
    int row = rid & 255;
    const float* r1 = (rid < 256 ? hu : an) + ((size_t)c * CB_ + row) * 64 + half * 32;
    float4 a4[8];
    float s1 = 0.f;
    #pragma unroll
    for (int t = 0; t < 8; t++) {
      a4[t] = ((const float4*)r1)[t];
      s1 += a4[t].x * a4[t].x + a4[t].y * a4[t].y + a4[t].z * a4[t].z + a4[t].w * a4[t].w;
    }
    s1 += __shfl_xor(s1, 1, 64);          // combine the two halves
    float inv = frcp(sqrtf(s1));
    if (half == 0) iN[rid] = inv;
    float sc = inv * SC_;
    #pragma unroll
    for (int t = 0; t < 4; t++) {
      f16x8 v;
      v[0] = (_Float16)(a4[2*t].x * sc);   v[1] = (_Float16)(a4[2*t].y * sc);
      v[2] = (_Float16)(a4[2*t].z * sc);   v[3] = (_Float16)(a4[2*t].w * sc);
      v[4] = (_Float16)(a4[2*t+1].x * sc); v[5] = (_Float16)(a4[2*t+1].y * sc);
      v[6] = (_Float16)(a4[2*t+1].z * sc); v[7] = (_Float16)(a4[2*t+1].w * sc);
      *(f16x8*)&Xh[rid * XS_ + half * 32 + t * 8] = v;
    }
  }
  __syncthreads();

  int l = tid & 63, wv = tid >> 6;       // wv 0..15
  int n = l & 15, q = l >> 4;
  int rb = wv * 32;
  f16x8 A[2][2];
  #pragma unroll
  for (int t = 0; t < 2; t++) {
    A[t][0] = *(const f16x8*)&Xh[(rb + t * 16 + n) * XS_ + q * 8];
    A[t][1] = *(const f16x8*)&Xh[(rb + t * 16 + n) * XS_ + 32 + q * 8];
  }
  float eNiR[2][4];
  #pragma unroll
  for (int t = 0; t < 2; t++)
    #pragma unroll
    for (int r = 0; r < 4; r++)
      eNiR[t][r] = EPS_ * iN[rb + t * 16 + q * 4 + r];
  float sums[2][4] = {{0,0,0,0},{0,0,0,0}};
  float labs2[2] = {0, 0};
  int selfn = q * 4;
  const floatx4 zero = {0.f, 0.f, 0.f, 0.f};
  for (int ct = 0; ct < 32; ct++) {
    f16x8 B0 = *(const f16x8*)&Xh[(ct * 16 + n) * XS_ + q * 8];
    f16x8 B1 = *(const f16x8*)&Xh[(ct * 16 + n) * XS_ + 32 + q * 8];
    float iNj = iN[ct * 16 + n];
    #pragma unroll
    for (int t = 0; t < 2; t++) {
      floatx4 acc = __builtin_amdgcn_mfma_f32_16x16x32_f16(A[t][0], B0, zero, 0, 0, 0);
      acc = __builtin_amdgcn_mfma_f32_16x16x32_f16(A[t][1], B1, acc, 0, 0, 0);
      int rtg = wv * 2 + t;
      if (ct == (rtg ^ 16)) {
        #pragma unroll
        for (int r = 0; r < 4; r++) {
          float G = acc[r];
          float u = eNiR[t][r] * iNj;
          float s2 = __builtin_fmaf(G, -u, G);
          sums[t][r] += fexp2(s2);
          if (n == selfn + r) labs2[t] += s2;
        }
      } else if (ct == rtg) {
        #pragma unroll
        for (int r = 0; r < 4; r++) {
          float G = acc[r];
          float u = eNiR[t][r] * iNj;
          float s2 = __builtin_fmaf(G, -u, G);
          float e = (n == selfn + r) ? 0.f : fexp2(s2);
          sums[t][r] += e;
        }
      } else {
        #pragma unroll
        for (int r = 0; r < 4; r++) {
          float G = acc[r];
          float u = eNiR[t][r] * iNj;
          float s2 = __builtin_fmaf(G, -u, G);
          sums[t][r] += fexp2(s2);
        }
      }
    }
  }
  #pragma unroll
  for (int off = 1; off <= 8; off <<= 1) {
    #pragma unroll
    for (int t = 0; t < 2; t++) {
      #pragma unroll
      for (int r = 0; r < 4; r++) sums[t][r] += __shfl_xor(sums[t][r], off, 64);
      labs2[t] += __shfl_xor(labs2[t], off, 64);
    }
  }
  float part = 0.f;
  if (n == 0) {
    #pragma unroll
    for (int t = 0; t < 2; t++) {
      float lt = 0.f;
      #pragma unroll
      for (int r = 0; r < 4; r++) lt += __logf(sums[t][r]);
      part += lt - labs2[t] * LN2_;
    }
  }
  #pragma unroll
  for (int off = 1; off < 64; off <<= 1) part += __shfl_xor(part, off, 64);
  if (l == 0) atomicAdd(loss_acc, part);
}

// ---------------- 6. scores (+ fused finalize): 4 edges per wave ----------
__global__ __launch_bounds__(256) void score_kernel(
    const float* __restrict__ hu, const float* __restrict__ hi,
    const int* __restrict__ pu, const int* __restrict__ pi,
    const int* __restrict__ nu, const int* __restrict__ ni,
    void* __restrict__ out, const float* __restrict__ flag,
    const float* __restrict__ loss_acc) {
  int isf32 = *flag > 0.5f;
  // finalize fused here: contrast kernel has retired (same stream), loss_acc is final
  if (blockIdx.x == 0 && threadIdx.x == 0) {
    float v = loss_acc[0] * (1.0f / (float)(2 * CB_ * NCHUNK_));
    if (isf32) ((float*)out)[2 * EP_] = v;
    else       ((__hip_bfloat16*)out)[2 * EP_] = __float2bfloat16(v);
  }
  int lane = threadIdx.x & 63;
  int g = lane >> 4, c = lane & 15;     // group 0..3, lane-in-group
  int gw = blockIdx.x * 4 + (threadIdx.x >> 6);
  int w = gw * 4 + g;                    // edge id, < 2*EP_
  int uu, ii;
  if (w < EP_) { uu = pu[w]; ii = pi[w]; }
  else         { uu = nu[w - EP_]; ii = ni[w - EP_]; }
  float4 a = *(const float4*)(hu + (size_t)uu * 64 + c * 4);
  float4 b = *(const float4*)(hi + (size_t)ii * 64 + c * 4);
  float p = a.x * b.x + a.y * b.y + a.z * b.z + a.w * b.w;
  #pragma unroll
  for (int off = 1; off < 16; off <<= 1) p += __shfl_xor(p, off, 64);
  if (c == 0) {
    if (isf32) ((float*)out)[w] = p;
    else       ((__hip_bfloat16*)out)[w] = __float2bfloat16(p);
  }
}

// ---------------- launch ----------------
extern "C" void kernel_launch(void* const* d_in, const int* in_sizes, int n_in,
                              void* d_out, int out_size, void* d_ws, size_t ws_size,
                              hipStream_t stream) {
  const void* ue  = d_in[0];
  const void* ie  = d_in[1];
  const void* W   = d_in[2];
  const void* a   = d_in[3];
  const void* WU  = d_in[4];
  const void* aU  = d_in[5];
  const void* cw  = d_in[6];
  const int* rs  = (const int*)d_in[7];
  const int* rd  = (const int*)d_in[8];
  const int* pu  = (const int*)d_in[9];
  const int* pi  = (const int*)d_in[10];
  const int* nu  = (const int*)d_in[11];
  const int* ni  = (const int*)d_in[12];
  const int* nbr = (const int*)d_in[13];

  float* wsf  = (float*)d_ws;
  int*   wsi  = (int*)d_ws;
  float* loss = wsf + OFF_LOSS;
  float* flag = wsf + OFF_FLAG;
  int* curU   = wsi + OFF_CURU;
  int* curI   = wsi + OFF_CURI;
  float* vecs = wsf + OFF_VEC;
  int* rowU   = wsi + OFF_ROWU;
  int* rowI   = wsi + OFF_ROWI;
  int* csrU   = wsi + OFF_CSRU;
  int* csrI   = wsi + OFF_CSRI;
  __hip_bfloat16* u1 = (__hip_bfloat16*)(wsf + OFF_U1);
  __hip_bfloat16* i1 = (__hip_bfloat16*)(wsf + OFF_I1);
  float* hu   = wsf + OFF_HU;
  float* hi   = wsf + OFF_HI;
  float* anc  = wsf + OFF_ANC;
  unsigned char* ue8 = (unsigned char*)(wsf + OFF_UE8);
  unsigned char* ie8 = (unsigned char*)(wsf + OFF_IE8);
  unsigned char* u18 = (unsigned char*)(wsf + OFF_U18);
  unsigned char* i18 = (unsigned char*)(wsf + OFF_I18);
  unsigned* bufU = (unsigned*)(wsf + OFF_HU);
  unsigned* bufI = (unsigned*)(wsf + OFF_HI);

  // prep also zeroes loss + bucket counters (memset launch removed)
  prep_kernel<<<1, 256, 0, stream>>>((const unsigned short*)ue, W, a, WU, aU,
                                     vecs, flag, wsf);

  // fused: CSR Phase A + anchor + fp8 convert (round-4 proven order)
  fusedA_kernel<<<NBA_ + NANC_ + NCVT_, 256, 0, stream>>>(
      rs, rd, bufU, bufI, curU, curI, ue, ie, WU, cw, vecs, nbr, anc, ue8, ie8, flag);

  // Phase B with per-block local scan
  bucketB_kernel<<<2 * NBK_, 256, 0, stream>>>(bufU, bufI, curU, curI,
                                               rowU, rowI, csrU, csrI);

  // fused layer-1 aggregation (fp8 dword gather, 16-edge unroll)
  agg1_kernel<<<(I_ + U_) / 4, 256, 0, stream>>>(ue8, ie8, rowU, rowI, csrU, csrI,
                                                 u1, i1, u18, i18);
  // fused layer-2 aggregation + attention (fp8 dword gather, 16-edge unroll)
  agg2attn_kernel<<<(I_ + U_) / 4, 256, 0, stream>>>(u18, i18, u1, i1, ue, ie,
                                                     rowU, rowI, csrU, csrI,
                                                     vecs, hu, hi, flag);

  // contrastive loss (dedicated CUs, 1024 threads)
  contrast_kernel<<<NCHUNK_, 1024, 0, stream>>>(hu, anc, loss);

  // scores + fused finalize (256-thr blocks, 4 edges/wave, high residency)
  score_kernel<<<NSCB_, 256, 0, stream>>>(hu, hi, pu, pi, nu, ni, d_out, flag, loss);
}

// Round 8
// 325.719 us; speedup vs baseline: 1.0465x; 1.0098x over previous
//
#include <hip/hip_runtime.h>
#include <hip/hip_bf16.h>

// ---------------- problem constants ----------------
constexpr int U_  = 51200;
constexpr int I_  = 25600;
constexpr int E_  = 1000000;
constexpr int EP_ = 100000;
constexpr int CB_ = 256;                 // contrastive chunk size
constexpr int NCHUNK_ = U_ / CB_;        // 200
constexpr size_t UD_ = (size_t)U_ * 64;
constexpr size_t ID_ = (size_t)I_ * 64;
constexpr int NBK_ = 200;                // buckets per side
constexpr int CAP_ = 8192;               // record slots per bucket
constexpr int TILE_ = 4096;              // edges per Phase-A block (proven best: round 4)
constexpr int NBA_ = (E_ + TILE_ - 1) / TILE_;  // 245
constexpr int NANC_ = U_ / 16;           // 3200 anchor blocks
constexpr int NCVT_ = (int)((UD_ + ID_) / (8 * 256));  // 2400 convert blocks (8 elem/thread)
constexpr int NSCB_ = (2 * EP_) / 16;    // 12500 score blocks (16 edges/block)

// fp8 scaling (values sit in e4m3 sweet range)
constexpr float SCALE_E_  = 16.f;   // raw embeddings ~0.1
constexpr float ISCALE_E_ = 1.f / 16.f;
constexpr float SCALE_1_  = 64.f;   // layer-1 aggregates ~0.02
constexpr float ISCALE_1_ = 1.f / 64.f;

// ---------------- workspace layout (4-byte element offsets) ----------------
constexpr size_t OFF_LOSS  = 0;
constexpr size_t OFF_FLAG  = 1;
constexpr size_t OFF_CURU  = 8;                      // 200 ints
constexpr size_t OFF_CURI  = 208;                    // 200 ints
constexpr size_t OFF_VEC   = 448;                    // 192 floats
constexpr size_t OFF_ROWU  = 1088;                   // U_+1
constexpr size_t OFF_ROWI  = ((OFF_ROWU + U_ + 1 + 63) / 64) * 64;   // I_+1
constexpr size_t OFF_CSRU  = ((OFF_ROWI + I_ + 1 + 63) / 64) * 64;   // E_
constexpr size_t OFF_CSRI  = OFF_CSRU + E_;          // E_
constexpr size_t OFF_U1    = ((OFF_CSRI + E_ + 63) / 64) * 64;       // UD_ (bf16)
constexpr size_t OFF_I1    = OFF_U1 + UD_;
constexpr size_t OFF_HU    = OFF_I1 + ID_;           // bufU aliases
constexpr size_t OFF_HI    = OFF_HU + UD_;           // bufI aliases
constexpr size_t OFF_ANC   = OFF_HI + ID_;
constexpr size_t OFF_UE8   = OFF_ANC + UD_;          // UD_ bytes (fp8)
constexpr size_t OFF_IE8   = OFF_UE8 + UD_ / 4;
constexpr size_t OFF_U18   = OFF_IE8 + ID_ / 4;
constexpr size_t OFF_I18   = OFF_U18 + UD_ / 4;
// total ≈ 65.6 MB

#define DEVI static __device__ __forceinline__

typedef _Float16 h2v __attribute__((ext_vector_type(2)));
typedef _Float16 f16x8 __attribute__((ext_vector_type(8)));
typedef float floatx4 __attribute__((ext_vector_type(4)));
typedef unsigned short u16x8 __attribute__((ext_vector_type(8)));

DEVI float b2f(__hip_bfloat16 x) { return __bfloat162float(x); }

DEVI float bfb2f(unsigned short b) {
  unsigned u = ((unsigned)b) << 16; float f; __builtin_memcpy(&f, &u, 4); return f;
}

DEVI float ldf(const void* p, size_t i, int isf32) {
  if (isf32) return ((const float*)p)[i];
  return b2f(((const __hip_bfloat16*)p)[i]);
}

DEVI float frcp(float x) { return __builtin_amdgcn_rcpf(x); }

DEVI float fexp2(float x) {
#if __has_builtin(__builtin_amdgcn_exp2f)
  return __builtin_amdgcn_exp2f(x);
#else
  return exp2f(x);
#endif
}

// fp8 e4m3 (OCP) decode/encode
DEVI float fp8_dec(unsigned v) {
#if __has_builtin(__builtin_amdgcn_cvt_f32_fp8)
  return __builtin_amdgcn_cvt_f32_fp8(v, 0);
#else
  unsigned b = v & 0xFF;
  if (!(b & 0x78)) return 0.f;  // flush subnormals (negligible at our scales)
  unsigned short h = (unsigned short)(((b & 0x80) << 8) | (((b & 0x7f) + (8 << 3)) << 7));
  _Float16 hf; __builtin_memcpy(&hf, &h, 2);
  return (float)hf;
#endif
}

// decode byte `s` (compile-time literal) of dword w
#if __has_builtin(__builtin_amdgcn_cvt_f32_fp8)
#define FP8D(w, s) __builtin_amdgcn_cvt_f32_fp8((w), (s))
#else
#define FP8D(w, s) fp8_dec(((w) >> (8 * (s))) & 0xFF)
#endif

DEVI unsigned fp8_enc_pk(float a, float b) {
#if __has_builtin(__builtin_amdgcn_cvt_pk_fp8_f32)
  return __builtin_amdgcn_cvt_pk_fp8_f32(a, b, 0u, false);
#else
  auto enc1 = [](float f) -> unsigned {
    _Float16 hf = (_Float16)f; unsigned short hb; __builtin_memcpy(&hb, &hf, 2);
    int s = hb >> 15, e = (hb >> 10) & 31, m = hb & 1023;
    int e8 = e - 15 + 7;
    int m3 = (m + ((1 << 6) + ((m >> 7) & 1))) >> 7;
    if (m3 > 7) { m3 = 0; e8++; }
    if (e8 <= 0) return (unsigned)(s << 7);
    if (e8 > 15) { e8 = 15; m3 = 6; }
    return (unsigned)((s << 7) | (e8 << 3) | m3);
  };
  return enc1(a) | (enc1(b) << 8);
#endif
}

DEVI int waveInclScan(int v, int lane) {
  #pragma unroll
  for (int off = 1; off < 64; off <<= 1) {
    int t = __shfl_up(v, off, 64);
    if (lane >= off) v += t;
  }
  return v;
}

// ---------------- 0. prep (zeroes counters; 256-thread vecs compute) ----------------
__global__ void prep_kernel(const unsigned short* __restrict__ ueu,
                            const void* __restrict__ W, const void* __restrict__ a,
                            const void* __restrict__ WU, const void* __restrict__ aU,
                            float* __restrict__ vecs, float* __restrict__ flag,
                            float* __restrict__ ws0) {
  int tid = threadIdx.x;
  for (int i = tid; i < 408; i += 256)
    if (i == 0 || i >= 8) ws0[i] = 0.f;
  int cnt = 0;
  for (int i = 0; i < 256; i++) {
    int e = (ueu[i] >> 7) & 0xFF;
    if (e >= 130) cnt++;
  }
  int isf32 = (cnt >= 8);
  if (tid == 0) *flag = isf32 ? 1.0f : 0.0f;
  // 4 threads per output dim d; each sums 16 e's, combine via 4-lane shfl
  int d = tid >> 2, q = tid & 3;
  float s = 0.f, t1 = 0.f, t2 = 0.f;
  for (int e = q * 16; e < q * 16 + 16; e++) {
    s += ldf(W, d * 64 + e, isf32) * ldf(a, e, isf32);
    float wue = ldf(WU, d * 64 + e, isf32);
    t1 += wue * ldf(aU, e, isf32);
    t2 += wue * ldf(aU, 64 + e, isf32);
  }
  s  += __shfl_xor(s, 1, 64);  s  += __shfl_xor(s, 2, 64);
  t1 += __shfl_xor(t1, 1, 64); t1 += __shfl_xor(t1, 2, 64);
  t2 += __shfl_xor(t2, 1, 64); t2 += __shfl_xor(t2, 2, 64);
  if (q == 0) {
    vecs[d] = s;
    vecs[64 + d] = t1;
    vecs[128 + d] = t2;
  }
}

// ---------------- fused A: bucketA + anchor (round-4 proven order) ------
struct BktSmem {            // ~39.4 KB at TILE_=4096
  int histU[NBK_], histI[NBK_];
  int loffU[NBK_ + 1], loffI[NBK_ + 1];
  int cbU[NBK_], cbI[NBK_];
  int lcU[NBK_], lcI[NBK_];
  int wsU[4], wsI[4];
  unsigned recsU[TILE_], recsI[TILE_];
};
constexpr int WS_ = 72;
struct AncSmem {            // ~11.6 KB
  _Float16 WUt[64 * WS_];
  _Float16 mixS[16 * WS_];
  float invSe[16];
  int nbrS[128];
};
constexpr size_t FSA_SMEM = sizeof(BktSmem) > sizeof(AncSmem) ? sizeof(BktSmem) : sizeof(AncSmem);

DEVI void bucketA_body(char* smemRaw, int blk,
    const int* __restrict__ rs, const int* __restrict__ rd,
    unsigned* __restrict__ bufU, unsigned* __restrict__ bufI,
    int* __restrict__ curU, int* __restrict__ curI) {
  BktSmem& S = *(BktSmem*)smemRaw;
  int tid = threadIdx.x;
  int base = blk * TILE_;
  for (int i = tid; i < NBK_; i += 256) { S.histU[i] = 0; S.histI[i] = 0; }
  __syncthreads();
  int ss[16], dd[16];
  #pragma unroll
  for (int t = 0; t < 16; t++) {
    int e = base + t * 256 + tid;
    bool v = e < E_;
    ss[t] = v ? rs[e] : -1;
    dd[t] = v ? rd[e] : 0;
    if (v) {
      atomicAdd(&S.histU[ss[t] >> 8], 1);
      atomicAdd(&S.histI[dd[t] >> 7], 1);
    }
  }
  __syncthreads();
  if (tid < NBK_) {
    int cU = S.histU[tid];
    S.cbU[tid] = tid * CAP_ + (cU ? atomicAdd(&curU[tid], cU) : 0);
    int cI = S.histI[tid];
    S.cbI[tid] = tid * CAP_ + (cI ? atomicAdd(&curI[tid], cI) : 0);
  }
  int lane = tid & 63, wv = tid >> 6;
  int cvU = (tid < NBK_) ? S.histU[tid] : 0;
  int cvI = (tid < NBK_) ? S.histI[tid] : 0;
  int inU = waveInclScan(cvU, lane);
  int inI = waveInclScan(cvI, lane);
  if (lane == 63) { S.wsU[wv] = inU; S.wsI[wv] = inI; }
  __syncthreads();
  int woU = 0, woI = 0;
  for (int w = 0; w < wv; w++) { woU += S.wsU[w]; woI += S.wsI[w]; }
  if (tid < NBK_) {
    S.loffU[tid] = woU + inU - cvU;
    S.loffI[tid] = woI + inI - cvI;
  }
  if (tid == NBK_ - 1) {
    S.loffU[NBK_] = woU + inU;
    S.loffI[NBK_] = woI + inI;
  }
  __syncthreads();
  if (tid < NBK_) { S.lcU[tid] = S.loffU[tid]; S.lcI[tid] = S.loffI[tid]; }
  __syncthreads();
  #pragma unroll
  for (int t = 0; t < 16; t++) {
    if (ss[t] >= 0) {
      int b = ss[t] >> 8;
      int p = atomicAdd(&S.lcU[b], 1);
      S.recsU[p] = ((unsigned)(ss[t] & 255) << 17) | (unsigned)dd[t];
      b = dd[t] >> 7;
      p = atomicAdd(&S.lcI[b], 1);
      S.recsI[p] = ((unsigned)(dd[t] & 127) << 17) | (unsigned)ss[t];
    }
  }
  __syncthreads();
  int totU = S.loffU[NBK_];
  for (int p = tid; p < totU; p += 256) {
    int lo = 0, hi = NBK_;
    while (hi - lo > 1) { int mid = (lo + hi) >> 1; if (S.loffU[mid] <= p) lo = mid; else hi = mid; }
    bufU[S.cbU[lo] + (p - S.loffU[lo])] = S.recsU[p];
  }
  int totI = S.loffI[NBK_];
  for (int p = tid; p < totI; p += 256) {
    int lo = 0, hi = NBK_;
    while (hi - lo > 1) { int mid = (lo + hi) >> 1; if (S.loffI[mid] <= p) lo = mid; else hi = mid; }
    bufI[S.cbI[lo] + (p - S.loffI[lo])] = S.recsI[p];
  }
}

// anchor: FFT-filter + neighbor attention (distributed multi-value reductions)
DEVI void anchor_body(char* smemRaw, int blk,
    const void* __restrict__ ue, const void* __restrict__ WU,
    const void* __restrict__ cw, const float* __restrict__ vecs,
    const int* __restrict__ nbr, float* __restrict__ out, int isf32) {
  AncSmem& S = *(AncSmem*)smemRaw;
  int tid = threadIdx.x;
  int wv = tid >> 6, lane = tid & 63;
  int ublk = blk * 16;

  #pragma unroll
  for (int it = 0; it < 16; it++) {
    int k = it * 4 + wv;
    S.WUt[lane * WS_ + k] = (_Float16)ldf(WU, (size_t)k * 64 + lane, isf32);
  }
  if (tid < 128) S.nbrS[tid] = nbr[ublk * 8 + tid];
  __syncthreads();

  float cw0 = ldf(cw, (0 * 64 + lane) * 2, isf32);
  float w1r = ldf(cw, (1 * 64 + lane) * 2, isf32), w1i = ldf(cw, (1 * 64 + lane) * 2 + 1, isf32);
  float w2r = ldf(cw, (2 * 64 + lane) * 2, isf32), w2i = ldf(cw, (2 * 64 + lane) * 2 + 1, isf32);
  float w3r = ldf(cw, (3 * 64 + lane) * 2, isf32), w3i = ldf(cw, (3 * 64 + lane) * 2 + 1, isf32);
  float cw4 = ldf(cw, (4 * 64 + lane) * 2, isf32);
  float v1 = vecs[64 + lane], v2 = vecs[128 + lane];
  const float c1 = 0.70710678118654752440f;

  bool b3 = (lane & 8) != 0, b4 = (lane & 16) != 0, b5 = (lane & 32) != 0;

  // q for the wave's 4 users: distributed reduce over lane-bit-{4,5}
  float qv0 = ldf(ue, (size_t)(ublk + wv * 4 + 0) * 64 + lane, isf32) * v2;
  float qv1 = ldf(ue, (size_t)(ublk + wv * 4 + 1) * 64 + lane, isf32) * v2;
  float qv2 = ldf(ue, (size_t)(ublk + wv * 4 + 2) * 64 + lane, isf32) * v2;
  float qv3 = ldf(ue, (size_t)(ublk + wv * 4 + 3) * 64 + lane, isf32) * v2;
  qv0 += __shfl_xor(qv0, 16, 64); qv0 += __shfl_xor(qv0, 32, 64);
  qv1 += __shfl_xor(qv1, 16, 64); qv1 += __shfl_xor(qv1, 32, 64);
  qv2 += __shfl_xor(qv2, 16, 64); qv2 += __shfl_xor(qv2, 32, 64);
  qv3 += __shfl_xor(qv3, 16, 64); qv3 += __shfl_xor(qv3, 32, 64);
  float qs0 = b4 ? qv1 : qv0;
  float qs1 = b4 ? qv3 : qv2;
  float qw = b5 ? qs1 : qs0;
  qw += __shfl_xor(qw, 1, 64); qw += __shfl_xor(qw, 2, 64);
  qw += __shfl_xor(qw, 4, 64); qw += __shfl_xor(qw, 8, 64);
  // lane l now holds Q[l>>4]

  float xc[8], xn[8];
  #pragma unroll
  for (int k = 0; k < 8; k++)
    xc[k] = ldf(ue, (size_t)S.nbrS[wv * 32 + k] * 64 + lane, isf32);

  for (int u4 = 0; u4 < 4; u4++) {
    int uL = wv * 4 + u4;
    if (u4 < 3) {
      #pragma unroll
      for (int k = 0; k < 8; k++)
        xn[k] = ldf(ue, (size_t)S.nbrS[wv * 32 + (u4 + 1) * 8 + k] * 64 + lane, isf32);
    }
    float sA = xc[1] - xc[3] - xc[5] + xc[7];
    float sB = xc[1] + xc[3] - xc[5] - xc[7];
    float ev = (xc[0] + xc[4]) + (xc[2] + xc[6]);
    float od = (xc[1] + xc[5]) + (xc[3] + xc[7]);
    float d04 = xc[0] - xc[4], d26 = xc[2] - xc[6];
    float X0r = ev + od;
    float X1r = d04 + c1 * sA;
    float X1i = -d26 - c1 * sB;
    float X2r = (xc[0] + xc[4]) - (xc[2] + xc[6]);
    float X2i = -(xc[1] - xc[3] + xc[5] - xc[7]);
    float X3r = d04 - c1 * sA;
    float X3i = d26 - c1 * sB;
    float X4r = ev - od;
    float Zr0 = X0r * cw0;
    float Zr1 = X1r * w1r - X1i * w1i, Zi1 = X1r * w1i + X1i * w1r;
    float Zr2 = X2r * w2r - X2i * w2i, Zi2 = X2r * w2i + X2i * w2r;
    float Zr3 = X3r * w3r - X3i * w3i, Zi3 = X3r * w3i + X3i * w3r;
    float Zr4 = X4r * cw4;
    float eP = Zr0 + Zr4, eM = Zr0 - Zr4;
    float t1 = c1 * (Zr1 - Zr3), t2 = c1 * (Zi1 + Zi3);
    float y[8];
    y[0] = eP + 2.f * (Zr1 + Zr2 + Zr3);
    y[1] = eM + 2.f * (t1 - t2 - Zi2);
    y[2] = eP + 2.f * (-Zi1 - Zr2 + Zi3);
    y[3] = eM + 2.f * (-t1 - t2 + Zi2);
    y[4] = eP + 2.f * (-Zr1 + Zr2 - Zr3);
    y[5] = eM + 2.f * (-t1 + t2 - Zi2);
    y[6] = eP + 2.f * (Zi1 - Zr2 - Zi3);
    y[7] = eM + 2.f * (t1 + t2 + Zi2);
    #pragma unroll
    for (int k = 0; k < 8; k++) y[k] *= 0.125f;

    // 8 dot-products vs v1: distributed reduce
    float p0 = y[0] * v1, p1 = y[1] * v1, p2 = y[2] * v1, p3 = y[3] * v1;
    float p4 = y[4] * v1, p5 = y[5] * v1, p6 = y[6] * v1, p7 = y[7] * v1;
    p0 += __shfl_xor(p0, 8, 64);  p0 += __shfl_xor(p0, 16, 64); p0 += __shfl_xor(p0, 32, 64);
    p1 += __shfl_xor(p1, 8, 64);  p1 += __shfl_xor(p1, 16, 64); p1 += __shfl_xor(p1, 32, 64);
    p2 += __shfl_xor(p2, 8, 64);  p2 += __shfl_xor(p2, 16, 64); p2 += __shfl_xor(p2, 32, 64);
    p3 += __shfl_xor(p3, 8, 64);  p3 += __shfl_xor(p3, 16, 64); p3 += __shfl_xor(p3, 32, 64);
    p4 += __shfl_xor(p4, 8, 64);  p4 += __shfl_xor(p4, 16, 64); p4 += __shfl_xor(p4, 32, 64);
    p5 += __shfl_xor(p5, 8, 64);  p5 += __shfl_xor(p5, 16, 64); p5 += __shfl_xor(p5, 32, 64);
    p6 += __shfl_xor(p6, 8, 64);  p6 += __shfl_xor(p6, 16, 64); p6 += __shfl_xor(p6, 32, 64);
    p7 += __shfl_xor(p7, 8, 64);  p7 += __shfl_xor(p7, 16, 64); p7 += __shfl_xor(p7, 32, 64);
    float a0 = b3 ? p1 : p0;
    float a1 = b3 ? p3 : p2;
    float a2 = b3 ? p5 : p4;
    float a3 = b3 ? p7 : p6;
    float c0 = b4 ? a1 : a0;
    float c1s = b4 ? a3 : a2;
    float w = b5 ? c1s : c0;
    w += __shfl_xor(w, 1, 64); w += __shfl_xor(w, 2, 64); w += __shfl_xor(w, 4, 64);
    // lane l holds EK[l>>3]

    float qu = __shfl(qw, u4 * 16, 64);
    float v = w + qu;
    v = v > 0.f ? v : 0.1f * v;              // LeakyReLU(0.1)
    float m = v;
    m = fmaxf(m, __shfl_xor(m, 8, 64));
    m = fmaxf(m, __shfl_xor(m, 16, 64));
    m = fmaxf(m, __shfl_xor(m, 32, 64));
    float wexp = __expf(v - m);
    float se = wexp;
    se += __shfl_xor(se, 8, 64); se += __shfl_xor(se, 16, 64); se += __shfl_xor(se, 32, 64);
    float mix = 0.f;
    #pragma unroll
    for (int k = 0; k < 8; k++)
      mix += __shfl(wexp, k * 8, 64) * y[k];
    S.mixS[uL * WS_ + lane] = (_Float16)mix;
    if (lane == 0) S.invSe[uL] = frcp(se);
    #pragma unroll
    for (int k = 0; k < 8; k++) xc[k] = xn[k];
  }
  __syncthreads();

  int n = lane & 15, qd = lane >> 4;
  f16x8 A0 = *(const f16x8*)&S.mixS[(lane & 15) * WS_ + qd * 8];
  f16x8 A1 = *(const f16x8*)&S.mixS[(lane & 15) * WS_ + 32 + qd * 8];
  f16x8 B0 = *(const f16x8*)&S.WUt[(wv * 16 + n) * WS_ + qd * 8];
  f16x8 B1 = *(const f16x8*)&S.WUt[(wv * 16 + n) * WS_ + 32 + qd * 8];
  const floatx4 zero = {0.f, 0.f, 0.f, 0.f};
  floatx4 acc = __builtin_amdgcn_mfma_f32_16x16x32_f16(A0, B0, zero, 0, 0, 0);
  acc = __builtin_amdgcn_mfma_f32_16x16x32_f16(A1, B1, acc, 0, 0, 0);
  #pragma unroll
  for (int r = 0; r < 4; r++) {
    int m = qd * 4 + r;
    out[(size_t)(ublk + m) * 64 + wv * 16 + n] = acc[r] * S.invSe[m];
  }
}

__global__ __launch_bounds__(256) void fusedA_kernel(
    const int* __restrict__ rs, const int* __restrict__ rd,
    unsigned* __restrict__ bufU, unsigned* __restrict__ bufI,
    int* __restrict__ curU, int* __restrict__ curI,
    const void* __restrict__ ue,
    const void* __restrict__ WU, const void* __restrict__ cw,
    const float* __restrict__ vecs, const int* __restrict__ nbr,
    float* __restrict__ anc, const float* __restrict__ flag) {
  __shared__ __align__(16) char smem[FSA_SMEM];
  // round-4 proven order: bucketA -> anchor (heterogeneous CU mix)
  if (blockIdx.x < NBA_) {
    bucketA_body(smem, blockIdx.x, rs, rd, bufU, bufI, curU, curI);
  } else {
    anchor_body(smem, blockIdx.x - NBA_, ue, WU, cw, vecs, nbr, anc, *flag > 0.5f);
  }
}

// 8 elements per thread, vector loads (fp32: 2×float4, bf16: 1×ushort8)
DEVI void convert_body(int blk, const void* __restrict__ ue, const void* __restrict__ ie,
                       unsigned char* __restrict__ ue8, unsigned char* __restrict__ ie8,
                       int isf32) {
  size_t t = (size_t)blk * 256 + threadIdx.x;   // 8-element group index
  const void* src; unsigned* dst; size_t o;
  if (t < UD_ / 8) { src = ue; dst = (unsigned*)ue8; o = t; }
  else             { src = ie; dst = (unsigned*)ie8; o = t - UD_ / 8; }
  float v[8];
  if (isf32) {
    float4 f0 = ((const float4*)src)[2 * o];
    float4 f1 = ((const float4*)src)[2 * o + 1];
    v[0] = f0.x; v[1] = f0.y; v[2] = f0.z; v[3] = f0.w;
    v[4] = f1.x; v[5] = f1.y; v[6] = f1.z; v[7] = f1.w;
  } else {
    u16x8 h = ((const u16x8*)src)[o];
    #pragma unroll
    for (int i = 0; i < 8; i++) v[i] = bfb2f(h[i]);
  }
  unsigned lo = fp8_enc_pk(v[0] * SCALE_E_, v[1] * SCALE_E_) |
                (fp8_enc_pk(v[2] * SCALE_E_, v[3] * SCALE_E_) << 16);
  unsigned hi = fp8_enc_pk(v[4] * SCALE_E_, v[5] * SCALE_E_) |
                (fp8_enc_pk(v[6] * SCALE_E_, v[7] * SCALE_E_) << 16);
  dst[2 * o]     = lo;
  dst[2 * o + 1] = hi;
}

// ---------------- 1c. Phase B (local bucket scan) + fp8 convert (fills idle CUs) ------
struct BktBSmem {
  int stage[CAP_];
  int cntk[256], offk[256];
  int exclS[256];
  int wsum[4], wsum2[4];
};

DEVI void bucketB_body(char* smemRaw, int b,
    const unsigned* __restrict__ bufU, const unsigned* __restrict__ bufI,
    const int* __restrict__ curU, const int* __restrict__ curI,
    int* __restrict__ rowU, int* __restrict__ rowI,
    int* __restrict__ csrU, int* __restrict__ csrI) {
  BktBSmem& S = *(BktBSmem*)smemRaw;
  int tid = threadIdx.x;
  int side = b >= NBK_;
  int bb = side ? b - NBK_ : b;
  const unsigned* src = (side ? bufI : bufU) + (size_t)bb * CAP_;
  const int* cur = side ? curI : curU;
  int total = cur[bb];
  int kpb   = side ? 128 : 256;
  int* rowptr = side ? rowI : rowU;
  int* csr    = side ? csrI : csrU;
  if (b == 0 && tid == 0) { rowU[U_] = E_; rowI[I_] = E_; }
  int lane = tid & 63, wv = tid >> 6;
  // local exclusive scan of cur[0..NBK_) -> gbase
  {
    int v = (tid < NBK_) ? cur[tid] : 0;
    int incl = waveInclScan(v, lane);
    if (lane == 63) S.wsum2[wv] = incl;
    S.cntk[tid] = 0;
    __syncthreads();
    int off = 0;
    for (int w = 0; w < wv; w++) off += S.wsum2[w];
    if (tid < NBK_) S.exclS[tid] = off + incl - v;
    __syncthreads();
  }
  int gbase = S.exclS[bb];
  for (int r = tid; r < total; r += 256) atomicAdd(&S.cntk[src[r] >> 17], 1);
  __syncthreads();
  int cv = (tid < kpb) ? S.cntk[tid] : 0;
  int incl = waveInclScan(cv, lane);
  if (lane == 63) S.wsum[wv] = incl;
  __syncthreads();
  int wvoff = 0;
  for (int w = 0; w < wv; w++) wvoff += S.wsum[w];
  int excl = wvoff + incl - cv;
  if (tid < kpb) {
    S.offk[tid] = excl;
    rowptr[bb * kpb + tid] = gbase + excl;
  }
  __syncthreads();
  for (int r = tid; r < total; r += 256) {
    unsigned rec = src[r];
    int slot = atomicAdd(&S.offk[rec >> 17], 1);
    if (slot < CAP_) S.stage[slot] = (int)(rec & 0x1FFFFu);
  }
  __syncthreads();
  for (int s = tid; s < total; s += 256) csr[gbase + s] = S.stage[s];
}

__global__ __launch_bounds__(256) void bucketB_kernel(
    const unsigned* __restrict__ bufU, const unsigned* __restrict__ bufI,
    const int* __restrict__ curU, const int* __restrict__ curI,
    int* __restrict__ rowU, int* __restrict__ rowI,
    int* __restrict__ csrU, int* __restrict__ csrI,
    const void* __restrict__ ue, const void* __restrict__ ie,
    unsigned char* __restrict__ ue8, unsigned char* __restrict__ ie8,
    const float* __restrict__ flag) {
  __shared__ __align__(16) char smem[sizeof(BktBSmem)];
  if (blockIdx.x < 2 * NBK_) {
    bucketB_body(smem, blockIdx.x, bufU, bufI, curU, curI, rowU, rowI, csrU, csrI);
  } else {
    convert_body(blockIdx.x - 2 * NBK_, ue, ie, ue8, ie8, *flag > 0.5f);
  }
}

// ---------------- 2. fused layer-1 aggregation (fp8 dwordx2 gather) -------
// lane = sub*8 + c8; each lane loads 8 B (8 fp8 cols) of edge csr[j+sub]; 8 edges/instr
__global__ __launch_bounds__(256) void agg1_kernel(
    const unsigned char* __restrict__ ue8, const unsigned char* __restrict__ ie8,
    const int* __restrict__ rowU, const int* __restrict__ rowI,
    const int* __restrict__ csrU, const int* __restrict__ csrI,
    __hip_bfloat16* __restrict__ u1, __hip_bfloat16* __restrict__ i1,
    unsigned char* __restrict__ u18, unsigned char* __restrict__ i18) {
  int wv = threadIdx.x >> 6, lane = threadIdx.x & 63;
  int sub = lane >> 3, c8 = lane & 7;
  int side = blockIdx.x >= I_ / 4;          // 0: item rows (gather ue8), 1: user rows
  int blk = side ? blockIdx.x - I_ / 4 : blockIdx.x;
  int r = blk * 4 + wv;
  const int* row = side ? rowU : rowI;
  const int* csr = side ? csrU : csrI;
  const unsigned char* src = side ? ie8 : ue8;
  __hip_bfloat16* out = side ? u1 : i1;
  unsigned char* out8 = side ? u18 : i18;
  int s0 = row[r], s1 = row[r + 1];
  float a8[8] = {0.f, 0.f, 0.f, 0.f, 0.f, 0.f, 0.f, 0.f};
  int j = s0;
  for (; j + 16 <= s1; j += 16) {        // 2 dwordx2 gathers in flight = 16 edges
    int e0 = csr[j + sub], e1 = csr[j + 8 + sub];
    uint2 w0 = *(const uint2*)(src + (size_t)e0 * 64 + c8 * 8);
    uint2 w1 = *(const uint2*)(src + (size_t)e1 * 64 + c8 * 8);
    a8[0] += FP8D(w0.x, 0) + FP8D(w1.x, 0);
    a8[1] += FP8D(w0.x, 1) + FP8D(w1.x, 1);
    a8[2] += FP8D(w0.x, 2) + FP8D(w1.x, 2);
    a8[3] += FP8D(w0.x, 3) + FP8D(w1.x, 3);
    a8[4] += FP8D(w0.y, 0) + FP8D(w1.y, 0);
    a8[5] += FP8D(w0.y, 1) + FP8D(w1.y, 1);
    a8[6] += FP8D(w0.y, 2) + FP8D(w1.y, 2);
    a8[7] += FP8D(w0.y, 3) + FP8D(w1.y, 3);
  }
  if (j + 8 <= s1) {
    int e0 = csr[j + sub];
    uint2 w0 = *(const uint2*)(src + (size_t)e0 * 64 + c8 * 8);
    a8[0] += FP8D(w0.x, 0); a8[1] += FP8D(w0.x, 1);
    a8[2] += FP8D(w0.x, 2); a8[3] += FP8D(w0.x, 3);
    a8[4] += FP8D(w0.y, 0); a8[5] += FP8D(w0.y, 1);
    a8[6] += FP8D(w0.y, 2); a8[7] += FP8D(w0.y, 3);
    j += 8;
  }
  int rem = s1 - j;
  if (sub < rem) {
    int e0 = csr[j + sub];
    uint2 w0 = *(const uint2*)(src + (size_t)e0 * 64 + c8 * 8);
    a8[0] += FP8D(w0.x, 0); a8[1] += FP8D(w0.x, 1);
    a8[2] += FP8D(w0.x, 2); a8[3] += FP8D(w0.x, 3);
    a8[4] += FP8D(w0.y, 0); a8[5] += FP8D(w0.y, 1);
    a8[6] += FP8D(w0.y, 2); a8[7] += FP8D(w0.y, 3);
  }
  #pragma unroll
  for (int c = 0; c < 8; c++) {
    a8[c] += __shfl_xor(a8[c], 8, 64);
    a8[c] += __shfl_xor(a8[c], 16, 64);
    a8[c] += __shfl_xor(a8[c], 32, 64);
  }
  // select value index = sub via compile-time-indexed cndmask tree (no scratch)
  bool sb0 = (sub & 1) != 0, sb1 = (sub & 2) != 0, sb2 = (sub & 4) != 0;
  float x0 = sb0 ? a8[1] : a8[0];
  float x1 = sb0 ? a8[3] : a8[2];
  float x2 = sb0 ? a8[5] : a8[4];
  float x3 = sb0 ? a8[7] : a8[6];
  float y0 = sb1 ? x1 : x0;
  float y1 = sb1 ? x3 : x2;
  float acc = sb2 ? y1 : y0;
  int col = c8 * 8 + sub;               // lane→column permutation
  float val = acc * ISCALE_E_ * frcp(fmaxf((float)(s1 - s0), 1.0f));
  size_t idx = (size_t)r * 64 + col;
  out[idx] = __float2bfloat16(val);
  unsigned p = fp8_enc_pk(val * SCALE_1_, val * SCALE_1_);
  out8[idx] = (unsigned char)(p & 0xFF);
}

// ---------------- 3. fused layer-2 aggregation + attention (fp8 dwordx2 gather) -------
__global__ __launch_bounds__(256) void agg2attn_kernel(
    const unsigned char* __restrict__ u18, const unsigned char* __restrict__ i18,
    const __hip_bfloat16* __restrict__ u1, const __hip_bfloat16* __restrict__ i1,
    const void* __restrict__ ue, const void* __restrict__ ie,
    const int* __restrict__ rowU, const int* __restrict__ rowI,
    const int* __restrict__ csrU, const int* __restrict__ csrI,
    const float* __restrict__ vecs, float* __restrict__ hu, float* __restrict__ hi,
    const float* __restrict__ flag) {
  int isf32 = *flag > 0.5f;
  int wv = threadIdx.x >> 6, lane = threadIdx.x & 63;
  int sub = lane >> 3, c8 = lane & 7;
  int side = blockIdx.x >= I_ / 4;          // 0: item rows, 1: user rows
  int blk = side ? blockIdx.x - I_ / 4 : blockIdx.x;
  int r = blk * 4 + wv;
  const int* row = side ? rowU : rowI;
  const int* csr = side ? csrU : csrI;
  const unsigned char* opp8 = side ? i18 : u18;
  const __hip_bfloat16* own1 = side ? u1 : i1;
  const void* base = side ? ue : ie;
  float* h = side ? hu : hi;
  int s0 = row[r], s1 = row[r + 1];
  float a8[8] = {0.f, 0.f, 0.f, 0.f, 0.f, 0.f, 0.f, 0.f};
  int j = s0;
  for (; j + 16 <= s1; j += 16) {
    int e0 = csr[j + sub], e1 = csr[j + 8 + sub];
    uint2 w0 = *(const uint2*)(opp8 + (size_t)e0 * 64 + c8 * 8);
    uint2 w1 = *(const uint2*)(opp8 + (size_t)e1 * 64 + c8 * 8);
    a8[0] += FP8D(w0.x, 0) + FP8D(w1.x, 0);
    a8[1] += FP8D(w0.x, 1) + FP8D(w1.x, 1);
    a8[2] += FP8D(w0.x, 2) + FP8D(w1.x, 2);
    a8[3] += FP8D(w0.x, 3) + FP8D(w1.x, 3);
    a8[4] += FP8D(w0.y, 0) + FP8D(w1.y, 0);
    a8[5] += FP8D(w0.y, 1) + FP8D(w1.y, 1);
    a8[6] += FP8D(w0.y, 2) + FP8D(w1.y, 2);
    a8[7] += FP8D(w0.y, 3) + FP8D(w1.y, 3);
  }
  if (j + 8 <= s1) {
    int e0 = csr[j + sub];
    uint2 w0 = *(const uint2*)(opp8 + (size_t)e0 * 64 + c8 * 8);
    a8[0] += FP8D(w0.x, 0); a8[1] += FP8D(w0.x, 1);
    a8[2] += FP8D(w0.x, 2); a8[3] += FP8D(w0.x, 3);
    a8[4] += FP8D(w0.y, 0); a8[5] += FP8D(w0.y, 1);
    a8[6] += FP8D(w0.y, 2); a8[7] += FP8D(w0.y, 3);
    j += 8;
  }
  int rem = s1 - j;
  if (sub < rem) {
    int e0 = csr[j + sub];
    uint2 w0 = *(const uint2*)(opp8 + (size_t)e0 * 64 + c8 * 8);
    a8[0] += FP8D(w0.x, 0); a8[1] += FP8D(w0.x, 1);
    a8[2] += FP8D(w0.x, 2); a8[3] += FP8D(w0.x, 3);
    a8[4] += FP8D(w0.y, 0); a8[5] += FP8D(w0.y, 1);
    a8[6] += FP8D(w0.y, 2); a8[7] += FP8D(w0.y, 3);
  }
  #pragma unroll
  for (int c = 0; c < 8; c++) {
    a8[c] += __shfl_xor(a8[c], 8, 64);
    a8[c] += __shfl_xor(a8[c], 16, 64);
    a8[c] += __shfl_xor(a8[c], 32, 64);
  }
  bool sb0 = (sub & 1) != 0, sb1 = (sub & 2) != 0, sb2 = (sub & 4) != 0;
  float x0 = sb0 ? a8[1] : a8[0];
  float x1 = sb0 ? a8[3] : a8[2];
  float x2 = sb0 ? a8[5] : a8[4];
  float x3 = sb0 ? a8[7] : a8[6];
  float y0 = sb1 ? x1 : x0;
  float y1 = sb1 ? x3 : x2;
  float acc = sb2 ? y1 : y0;
  int col = c8 * 8 + sub;               // lane→column permutation
  size_t idx = (size_t)r * 64 + col;
  float t2 = acc * ISCALE_1_ * frcp(fmaxf((float)(s1 - s0), 1.0f));
  float t0 = ldf(base, idx, isf32);
  float t1 = b2f(own1[idx]);
  float w = vecs[col];   // Wa
  float p0 = t0 * w, p1 = t1 * w, p2 = t2 * w;
  #pragma unroll
  for (int off = 32; off; off >>= 1) {
    p0 += __shfl_xor(p0, off, 64);
    p1 += __shfl_xor(p1, off, 64);
    p2 += __shfl_xor(p2, off, 64);
  }
  float m = fmaxf(p0, fmaxf(p1, p2));
  float e0 = __expf(p0 - m), e1 = __expf(p1 - m), e2 = __expf(p2 - m);
  float inv = 1.0f / (e0 + e1 + e2);
  h[idx] = (t0 * e0 + t1 * e1 + t2 * e2) * inv;
}

// ---------------- 5. contrastive loss: slim epilogue MFMA Gram ----------
constexpr int XS_ = 72;                   // f16 row stride (144 B)
constexpr float SC_  = 2.6857914f;        // sqrt(5*log2(e))
constexpr float EPS_ = 1e-6f;
constexpr float LN2_ = 0.6931471805599453f;
__global__ __launch_bounds__(1024) void contrast_kernel(
    const float* __restrict__ hu, const float* __restrict__ an,
    float* __restrict__ loss_acc) {
  __shared__ __align__(16) _Float16 Xh[512 * XS_];  // 72 KB
  __shared__ float iN[512];
  int tid = threadIdx.x;
  int c = blockIdx.x;

  // phase 1: all 1024 threads, 2 threads per row (half-row each)
  {
    int rid = tid >> 1, half = tid & 1;   // rid 0..511
    int row = rid & 255;
    const float* r1 = (rid < 256 ? hu : an) + ((size_t)c * CB_ + row) * 64 + half * 32;
    float4 a4[8];
    float s1 = 0.f;
    #pragma unroll
    for (int t = 0; t < 8; t++) {
      a4[t] = ((const float4*)r1)[t];
      s1 += a4[t].x * a4[t].x + a4[t].y * a4[t].y + a4[t].z * a4[t].z + a4[t].w * a4[t].w;
    }
    s1 += __shfl_xor(s1, 1, 64);          // combine the two halves
    float inv = frcp(sqrtf(s1));
    if (half == 0) iN[rid] = inv;
    float sc = inv * SC_;
    #pragma unroll
    for (int t = 0; t < 4; t++) {
      f16x8 v;
      v[0] = (_Float16)(a4[2*t].x * sc);   v[1] = (_Float16)(a4[2*t].y * sc);
      v[2] = (_Float16)(a4[2*t].z * sc);   v[3] = (_Float16)(a4[2*t].w * sc);
      v[4] = (_Float16)(a4[2*t+1].x * sc); v[5] = (_Float16)(a4[2*t+1].y * sc);
      v[6] = (_Float16)(a4[2*t+1].z * sc); v[7] = (_Float16)(a4[2*t+1].w * sc);
      *(f16x8*)&Xh[rid * XS_ + half * 32 + t * 8] = v;
    }
  }
  __syncthreads();

  int l = tid & 63, wv = tid >> 6;       // wv 0..15
  int n = l & 15, q = l >> 4;
  int rb = wv * 32;
  f16x8 A[2][2];
  #pragma unroll
  for (int t = 0; t < 2; t++) {
    A[t][0] = *(const f16x8*)&Xh[(rb + t * 16 + n) * XS_ + q * 8];
    A[t][1] = *(const f16x8*)&Xh[(rb + t * 16 + n) * XS_ + 32 + q * 8];
  }
  float eNiR[2][4];
  #pragma unroll
  for (int t = 0; t < 2; t++)
    #pragma unroll
    for (int r = 0; r < 4; r++)
      eNiR[t][r] = EPS_ * iN[rb + t * 16 + q * 4 + r];
  float sums[2][4] = {{0,0,0,0},{0,0,0,0}};
  float labs2[2] = {0, 0};
  int selfn = q * 4;
  const floatx4 zero = {0.f, 0.f, 0.f, 0.f};
  for (int ct = 0; ct < 32; ct++) {
    f16x8 B0 = *(const f16x8*)&Xh[(ct * 16 + n) * XS_ + q * 8];
    f16x8 B1 = *(const f16x8*)&Xh[(ct * 16 + n) * XS_ + 32 + q * 8];
    float iNj = iN[ct * 16 + n];
    #pragma unroll
    for (int t = 0; t < 2; t++) {
      floatx4 acc = __builtin_amdgcn_mfma_f32_16x16x32_f16(A[t][0], B0, zero, 0, 0, 0);
      acc = __builtin_amdgcn_mfma_f32_16x16x32_f16(A[t][1], B1, acc, 0, 0, 0);
      int rtg = wv * 2 + t;
      if (ct == (rtg ^ 16)) {
        #pragma unroll
        for (int r = 0; r < 4; r++) {
          float G = acc[r];
          float u = eNiR[t][r] * iNj;
          float s2 = __builtin_fmaf(G, -u, G);
          sums[t][r] += fexp2(s2);
          if (n == selfn + r) labs2[t] += s2;
        }
      } else if (ct == rtg) {
        #pragma unroll
        for (int r = 0; r < 4; r++) {
          float G = acc[r];
          float u = eNiR[t][r] * iNj;
          float s2 = __builtin_fmaf(G, -u, G);
          float e = (n == selfn + r) ? 0.f : fexp2(s2);
          sums[t][r] += e;
        }
      } else {
        #pragma unroll
        for (int r = 0; r < 4; r++) {
          float G = acc[r];
          float u = eNiR[t][r] * iNj;
          float s2 = __builtin_fmaf(G, -u, G);
          sums[t][r] += fexp2(s2);
        }
      }
    }
  }
  #pragma unroll
  for (int off = 1; off <= 8; off <<= 1) {
    #pragma unroll
    for (int t = 0; t < 2; t++) {
      #pragma unroll
      for (int r = 0; r < 4; r++) sums[t][r] += __shfl_xor(sums[t][r], off, 64);
      labs2[t] += __shfl_xor(labs2[t], off, 64);
    }
  }
  float part = 0.f;
  if (n == 0) {
    #pragma unroll
    for (int t = 0; t < 2; t++) {
      float lt = 0.f;
      #pragma unroll
      for (int r = 0; r < 4; r++) lt += __logf(sums[t][r]);
      part += lt - labs2[t] * LN2_;
    }
  }
  #pragma unroll
  for (int off = 1; off < 64; off <<= 1) part += __shfl_xor(part, off, 64);
  if (l == 0) atomicAdd(loss_acc, part);
}

// ---------------- 6. scores (+ fused finalize): 4 edges per wave ----------
__global__ __launch_bounds__(256) void score_kernel(
    const float* __restrict__ hu, const float* __restrict__ hi,
    const int* __restrict__ pu, const int* __restrict__ pi,
    const int* __restrict__ nu, const int* __restrict__ ni,
    void* __restrict__ out, const float* __restrict__ flag,
    const float* __restrict__ loss_acc) {
  int isf32 = *flag > 0.5f;
  // finalize fused here: contrast kernel has retired (same stream), loss_acc is final
  if (blockIdx.x == 0 && threadIdx.x == 0) {
    float v = loss_acc[0] * (1.0f / (float)(2 * CB_ * NCHUNK_));
    if (isf32) ((float*)out)[2 * EP_] = v;
    else       ((__hip_bfloat16*)out)[2 * EP_] = __float2bfloat16(v);
  }
  int lane = threadIdx.x & 63;
  int g = lane >> 4, c = lane & 15;     // group 0..3, lane-in-group
  int gw = blockIdx.x * 4 + (threadIdx.x >> 6);
  int w = gw * 4 + g;                    // edge id, < 2*EP_
  int uu, ii;
  if (w < EP_) { uu = pu[w]; ii = pi[w]; }
  else         { uu = nu[w - EP_]; ii = ni[w - EP_]; }
  float4 a = *(const float4*)(hu + (size_t)uu * 64 + c * 4);
  float4 b = *(const float4*)(hi + (size_t)ii * 64 + c * 4);
  float p = a.x * b.x + a.y * b.y + a.z * b.z + a.w * b.w;
  #pragma unroll
  for (int off = 1; off < 16; off <<= 1) p += __shfl_xor(p, off, 64);
  if (c == 0) {
    if (isf32) ((float*)out)[w] = p;
    else       ((__hip_bfloat16*)out)[w] = __float2bfloat16(p);
  }
}

// ---------------- launch ----------------
extern "C" void kernel_launch(void* const* d_in, const int* in_sizes, int n_in,
                              void* d_out, int out_size, void* d_ws, size_t ws_size,
                              hipStream_t stream) {
  const void* ue  = d_in[0];
  const void* ie  = d_in[1];
  const void* W   = d_in[2];
  const void* a   = d_in[3];
  const void* WU  = d_in[4];
  const void* aU  = d_in[5];
  const void* cw  = d_in[6];
  const int* rs  = (const int*)d_in[7];
  const int* rd  = (const int*)d_in[8];
  const int* pu  = (const int*)d_in[9];
  const int* pi  = (const int*)d_in[10];
  const int* nu  = (const int*)d_in[11];
  const int* ni  = (const int*)d_in[12];
  const int* nbr = (const int*)d_in[13];

  float* wsf  = (float*)d_ws;
  int*   wsi  = (int*)d_ws;
  float* loss = wsf + OFF_LOSS;
  float* flag = wsf + OFF_FLAG;
  int* curU   = wsi + OFF_CURU;
  int* curI   = wsi + OFF_CURI;
  float* vecs = wsf + OFF_VEC;
  int* rowU   = wsi + OFF_ROWU;
  int* rowI   = wsi + OFF_ROWI;
  int* csrU   = wsi + OFF_CSRU;
  int* csrI   = wsi + OFF_CSRI;
  __hip_bfloat16* u1 = (__hip_bfloat16*)(wsf + OFF_U1);
  __hip_bfloat16* i1 = (__hip_bfloat16*)(wsf + OFF_I1);
  float* hu   = wsf + OFF_HU;
  float* hi   = wsf + OFF_HI;
  float* anc  = wsf + OFF_ANC;
  unsigned char* ue8 = (unsigned char*)(wsf + OFF_UE8);
  unsigned char* ie8 = (unsigned char*)(wsf + OFF_IE8);
  unsigned char* u18 = (unsigned char*)(wsf + OFF_U18);
  unsigned char* i18 = (unsigned char*)(wsf + OFF_I18);
  unsigned* bufU = (unsigned*)(wsf + OFF_HU);
  unsigned* bufI = (unsigned*)(wsf + OFF_HI);

  // prep also zeroes loss + bucket counters (memset launch removed)
  prep_kernel<<<1, 256, 0, stream>>>((const unsigned short*)ue, W, a, WU, aU,
                                     vecs, flag, wsf);

  // fused: CSR Phase A + anchor (round-4 proven order, convert moved to bucketB)
  fusedA_kernel<<<NBA_ + NANC_, 256, 0, stream>>>(
      rs, rd, bufU, bufI, curU, curI, ue, WU, cw, vecs, nbr, anc, flag);

  // Phase B with per-block local scan + fp8 convert filling idle CUs
  bucketB_kernel<<<2 * NBK_ + NCVT_, 256, 0, stream>>>(
      bufU, bufI, curU, curI, rowU, rowI, csrU, csrI, ue, ie, ue8, ie8, flag);

  // fused layer-1 aggregation (fp8 dwordx2 gather, 16-edge unroll)
  agg1_kernel<<<(I_ + U_) / 4, 256, 0, stream>>>(ue8, ie8, rowU, rowI, csrU, csrI,
                                                 u1, i1, u18, i18);
  // fused layer-2 aggregation + attention (fp8 dwordx2 gather, 16-edge unroll)
  agg2attn_kernel<<<(I_ + U_) / 4, 256, 0, stream>>>(u18, i18, u1, i1, ue, ie,
                                                     rowU, rowI, csrU, csrI,
                                                     vecs, hu, hi, flag);

  // contrastive loss (dedicated CUs, 1024 threads)
  contrast_kernel<<<NCHUNK_, 1024, 0, stream>>>(hu, anc, loss);

  // scores + fused finalize (256-thr blocks, 4 edges/wave, high residency)
  score_kernel<<<NSCB_, 256, 0, stream>>>(hu, hi, pu, pi, nu, ni, d_out, flag, loss);
}